// Round 5
// baseline (241.927 us; speedup 1.0000x reference)
//
#include <hip/hip_runtime.h>
#include <stdint.h>

typedef short bf16x4 __attribute__((ext_vector_type(4)));
typedef short bf16x8 __attribute__((ext_vector_type(8)));
typedef _Float16 f16x8 __attribute__((ext_vector_type(8)));
typedef float f32x4 __attribute__((ext_vector_type(4)));
typedef float f32x16 __attribute__((ext_vector_type(16)));
typedef unsigned int u32x4 __attribute__((ext_vector_type(4)));
typedef unsigned int u32x2 __attribute__((ext_vector_type(2)));

#if __has_builtin(__builtin_amdgcn_exp2f)
#define EXP2 __builtin_amdgcn_exp2f
#else
#define EXP2 exp2f
#endif

// ---------- helpers ----------
__device__ __forceinline__ short f2bf(float f) {  // RNE f32->bf16 (finite inputs)
  union { float f; uint32_t u; } v; v.f = f;
  uint32_t r = (v.u + 0x7fffu + ((v.u >> 16) & 1u)) >> 16;
  return (short)(uint16_t)r;
}

__device__ __forceinline__ unsigned cvtpk_bf16(float lo, float hi) {
  unsigned r;
  asm("v_cvt_pk_bf16_f32 %0, %1, %2" : "=v"(r) : "v"(lo), "v"(hi));
  return r;
}

// v_permlane32_swap_b32 via the BUILTIN: the compiler models the opcode's
// VALU-write->permlane-read wait-state hazard (raw inline asm does not get
// hazard NOPs inserted inside/around it -- the round-3/4 failure mode).
#if __has_builtin(__builtin_amdgcn_permlane32_swap)
__device__ __forceinline__ void plane32_swap(unsigned& a, unsigned& b) {
  u32x2 r = __builtin_amdgcn_permlane32_swap(a, b, false, false);
  a = r[0]; b = r[1];
}
__device__ __forceinline__ float xhalf_max(float x) {
  unsigned xu = __builtin_bit_cast(unsigned, x);
  u32x2 r = __builtin_amdgcn_permlane32_swap(xu, xu, false, false);
  return fmaxf(__builtin_bit_cast(float, r[0]), __builtin_bit_cast(float, r[1]));
}
__device__ __forceinline__ float xhalf_sum(float x) {
  unsigned xu = __builtin_bit_cast(unsigned, x);
  u32x2 r = __builtin_amdgcn_permlane32_swap(xu, xu, false, false);
  return __builtin_bit_cast(float, r[0]) + __builtin_bit_cast(float, r[1]);
}
#else
__device__ __forceinline__ void plane32_swap(unsigned& a, unsigned& b) {
  asm("s_nop 1\n\tv_permlane32_swap_b32 %0, %1" : "+v"(a), "+v"(b));
}
__device__ __forceinline__ float xhalf_max(float x) { return fmaxf(x, __shfl_xor(x, 32, 64)); }
__device__ __forceinline__ float xhalf_sum(float x) { return x + __shfl_xor(x, 32, 64); }
#endif

__device__ __forceinline__ float fmax3(float a, float b, float c) {
  return fmaxf(fmaxf(a, b), c);  // clang fuses to v_max3_f32
}

__device__ __forceinline__ f32x16 zero16() {
  f32x16 z;
#pragma unroll
  for (int i = 0; i < 16; ++i) z[i] = 0.f;
  return z;
}

__device__ __forceinline__ void gld_lds16(const void* g, void* l) {
  __builtin_amdgcn_global_load_lds(
      (__attribute__((address_space(1))) const void*)g,
      (__attribute__((address_space(3))) void*)l, 16, 0, 0);
}

// ---------- RMSNorm + cast to bf16 ----------
__global__ __launch_bounds__(256) void k_rmsnorm(const float* __restrict__ x,
                                                 const float* __restrict__ wn,
                                                 short* __restrict__ xn) {
  const int row = blockIdx.x;      // 8192 rows
  const int t = threadIdx.x;       // 256 threads, 4 floats each
  const float4 v = reinterpret_cast<const float4*>(x + (size_t)row * 1024)[t];
  float ss = v.x * v.x + v.y * v.y + v.z * v.z + v.w * v.w;
#pragma unroll
  for (int m = 32; m >= 1; m >>= 1) ss += __shfl_xor(ss, m, 64);
  __shared__ float red[4];
  if ((t & 63) == 0) red[t >> 6] = ss;
  __syncthreads();
  const float tot = red[0] + red[1] + red[2] + red[3];
  const float rr = rsqrtf(tot * (1.0f / 1024.0f) + 1e-5f);
  const float4 g = reinterpret_cast<const float4*>(wn)[t];
  bf16x4 o;
  o[0] = f2bf(v.x * rr * g.x);
  o[1] = f2bf(v.y * rr * g.y);
  o[2] = f2bf(v.z * rr * g.z);
  o[3] = f2bf(v.w * rr * g.w);
  reinterpret_cast<bf16x4*>(xn + (size_t)row * 1024)[t] = o;
}

// ---------- casts ----------
__global__ __launch_bounds__(256) void k_cast_bf(const float* __restrict__ in,
                                                 short* __restrict__ out, int n4) {
  int i = blockIdx.x * 256 + threadIdx.x;
  if (i >= n4) return;
  float4 v = reinterpret_cast<const float4*>(in)[i];
  bf16x4 o;
  o[0] = f2bf(v.x); o[1] = f2bf(v.y); o[2] = f2bf(v.z); o[3] = f2bf(v.w);
  reinterpret_cast<bf16x4*>(out)[i] = o;
}

__global__ __launch_bounds__(256) void k_cast_f16(const float* __restrict__ in,
                                                  _Float16* __restrict__ out, int n4) {
  int i = blockIdx.x * 256 + threadIdx.x;
  if (i >= n4) return;
  float4 v = reinterpret_cast<const float4*>(in)[i];
  _Float16 o[4] = {(_Float16)v.x, (_Float16)v.y, (_Float16)v.z, (_Float16)v.w};
  reinterpret_cast<ulong1*>(out)[i] = *reinterpret_cast<ulong1*>(o);
}

// ---------- QKV GEMM (bf16, m97 structure, 128x128xBK32, T1 XCD swizzle) ----------
__global__ __launch_bounds__(256) void k_gemm_qkv(const short* __restrict__ A,
                                                  const short* __restrict__ B,
                                                  const float* __restrict__ bias,
                                                  short* __restrict__ qb,
                                                  short* __restrict__ kb,
                                                  short* __restrict__ vb) {
  __shared__ __align__(16) short As[128 * 32];
  __shared__ __align__(16) short Bs[128 * 32];
  const int t = threadIdx.x;
  // T1: XCD-aware remap (nwg = 24*64 = 1536, 1536%8==0)
  const int orig = blockIdx.y * 24 + blockIdx.x;
  const int swz = (orig & 7) * 192 + (orig >> 3);
  const long bn0 = (long)(swz % 24) * 128;
  const long bm0 = (long)(swz / 24) * 128;
  const int w = t >> 6, l = t & 63;
  const int wr = (w >> 1) * 64, wc = (w & 1) * 64;
  const int lm = l & 15, h = l >> 4;
  f32x4 acc[4][4];
#pragma unroll
  for (int i = 0; i < 4; ++i)
#pragma unroll
    for (int j = 0; j < 4; ++j) acc[i][j] = (f32x4){0.f, 0.f, 0.f, 0.f};
  const int srow = t >> 2, scol = (t & 3) * 8;
  const short* Ag = A + (bm0 + srow) * 1024 + scol;
  const short* Bg = B + (bn0 + srow) * 1024 + scol;
  short* AsP = As + t * 8;
  short* BsP = Bs + t * 8;
  for (int kt = 0; kt < 32; ++kt) {
    const int k0 = kt << 5;
    gld_lds16(Ag + k0, AsP);
    gld_lds16(Ag + k0 + 64 * 1024, AsP + 2048);
    gld_lds16(Bg + k0, BsP);
    gld_lds16(Bg + k0 + 64 * 1024, BsP + 2048);
    __syncthreads();
    bf16x8 af[4], bfr[4];
#pragma unroll
    for (int mi = 0; mi < 4; ++mi)
      af[mi] = *reinterpret_cast<const bf16x8*>(As + (wr + mi * 16 + lm) * 32 + h * 8);
#pragma unroll
    for (int ni = 0; ni < 4; ++ni)
      bfr[ni] = *reinterpret_cast<const bf16x8*>(Bs + (wc + ni * 16 + lm) * 32 + h * 8);
    __builtin_amdgcn_s_setprio(1);
#pragma unroll
    for (int mi = 0; mi < 4; ++mi)
#pragma unroll
      for (int ni = 0; ni < 4; ++ni)
        acc[mi][ni] = __builtin_amdgcn_mfma_f32_16x16x32_bf16(af[mi], bfr[ni], acc[mi][ni], 0, 0, 0);
    __builtin_amdgcn_s_setprio(0);
    __syncthreads();
  }
#pragma unroll
  for (int ni = 0; ni < 4; ++ni) {
    const int ncol = (int)bn0 + wc + ni * 16 + lm;
    const float bv = bias[ncol];
    const int which = ncol >> 10;
    const int e = ncol & 1023;
#pragma unroll
    for (int mi = 0; mi < 4; ++mi) {
#pragma unroll
      for (int r = 0; r < 4; ++r) {
        const long mrow = bm0 + wr + mi * 16 + h * 4 + r;
        const float val = acc[mi][ni][r] + bv;
        const long off = (((mrow >> 11) * 16 + (e >> 6)) * 2048 + (mrow & 2047)) * 64 + (e & 63);
        if (which == 0) qb[off] = f2bf(val * 0.18033688011112042f);  // 0.125*log2(e)
        else if (which == 1) kb[off] = f2bf(val);
        else vb[off] = f2bf(val);
      }
    }
  }
}

// ---------- out-proj GEMM (fp16 inputs for precision, fp32 out) ----------
__global__ __launch_bounds__(256) void k_gemm_out(const _Float16* __restrict__ A,
                                                  const _Float16* __restrict__ B,
                                                  const float* __restrict__ bias,
                                                  float* __restrict__ outp) {
  __shared__ __align__(16) _Float16 As[128 * 32];
  __shared__ __align__(16) _Float16 Bs[128 * 32];
  const int t = threadIdx.x;
  // T1: nwg = 8*64 = 512, 512%8==0
  const int orig = blockIdx.y * 8 + blockIdx.x;
  const int swz = (orig & 7) * 64 + (orig >> 3);
  const long bn0 = (long)(swz % 8) * 128;
  const long bm0 = (long)(swz / 8) * 128;
  const int w = t >> 6, l = t & 63;
  const int wr = (w >> 1) * 64, wc = (w & 1) * 64;
  const int lm = l & 15, h = l >> 4;
  f32x4 acc[4][4];
#pragma unroll
  for (int i = 0; i < 4; ++i)
#pragma unroll
    for (int j = 0; j < 4; ++j) acc[i][j] = (f32x4){0.f, 0.f, 0.f, 0.f};
  const int srow = t >> 2, scol = (t & 3) * 8;
  const _Float16* Ag = A + (bm0 + srow) * 1024 + scol;
  const _Float16* Bg = B + (bn0 + srow) * 1024 + scol;
  _Float16* AsP = As + t * 8;
  _Float16* BsP = Bs + t * 8;
  for (int kt = 0; kt < 32; ++kt) {
    const int k0 = kt << 5;
    gld_lds16(Ag + k0, AsP);
    gld_lds16(Ag + k0 + 64 * 1024, AsP + 2048);
    gld_lds16(Bg + k0, BsP);
    gld_lds16(Bg + k0 + 64 * 1024, BsP + 2048);
    __syncthreads();
    f16x8 af[4], bfr[4];
#pragma unroll
    for (int mi = 0; mi < 4; ++mi)
      af[mi] = *reinterpret_cast<const f16x8*>(As + (wr + mi * 16 + lm) * 32 + h * 8);
#pragma unroll
    for (int ni = 0; ni < 4; ++ni)
      bfr[ni] = *reinterpret_cast<const f16x8*>(Bs + (wc + ni * 16 + lm) * 32 + h * 8);
    __builtin_amdgcn_s_setprio(1);
#pragma unroll
    for (int mi = 0; mi < 4; ++mi)
#pragma unroll
      for (int ni = 0; ni < 4; ++ni)
        acc[mi][ni] = __builtin_amdgcn_mfma_f32_16x16x32_f16(af[mi], bfr[ni], acc[mi][ni], 0, 0, 0);
    __builtin_amdgcn_s_setprio(0);
    __syncthreads();
  }
#pragma unroll
  for (int ni = 0; ni < 4; ++ni) {
    const int ncol = (int)bn0 + wc + ni * 16 + lm;
    const float bv = bias[ncol];
#pragma unroll
    for (int mi = 0; mi < 4; ++mi) {
#pragma unroll
      for (int r = 0; r < 4; ++r) {
        const long mrow = bm0 + wr + mi * 16 + h * 4 + r;
        outp[mrow * 1024 + ncol] = acc[mi][ni][r] + bv;
      }
    }
  }
}

// ---------- V transpose: v[BH][S][64] -> vT[BH][64][S] ----------
__global__ __launch_bounds__(256) void k_transpose_v(const short* __restrict__ v,
                                                     short* __restrict__ vt) {
  __shared__ short tile[64][72];
  const int bh = blockIdx.y, st = blockIdx.x;  // 32 s-tiles of 64
  const int t = threadIdx.x;
  const int r = t >> 2, c0 = (t & 3) * 16;
  const short* src = v + ((size_t)(bh * 2048 + st * 64 + r)) * 64 + c0;
  bf16x8 a = *reinterpret_cast<const bf16x8*>(src);
  bf16x8 b = *reinterpret_cast<const bf16x8*>(src + 8);
#pragma unroll
  for (int j = 0; j < 8; ++j) tile[r][c0 + j] = a[j];
#pragma unroll
  for (int j = 0; j < 8; ++j) tile[r][c0 + 8 + j] = b[j];
  __syncthreads();
  __align__(16) short tmp[16];
#pragma unroll
  for (int j = 0; j < 16; ++j) tmp[j] = tile[c0 + j][r];
  short* dst = vt + ((size_t)(bh * 64 + r)) * 2048 + st * 64 + c0;
  *reinterpret_cast<bf16x8*>(dst) = *reinterpret_cast<const bf16x8*>(tmp);
  *reinterpret_cast<bf16x8*>(dst + 8) = *reinterpret_cast<const bf16x8*>(tmp + 8);
}

// ---------- flash attention v3c ----------
// v2 + (a) cross-half reductions via builtin permlane32_swap (hazard-safe),
// (b) per-half partial lr combined once at the end, (c) setprio around MFMA
// clusters, (d) v_max3 max tree.
__global__ __launch_bounds__(256) void k_attn(const short* __restrict__ q,
                                              const short* __restrict__ k,
                                              const short* __restrict__ vt,
                                              _Float16* __restrict__ o) {
  __shared__ __align__(16) short Ks[2][4096];  // 8KB x2
  __shared__ __align__(16) short Vs[2][4096];  // 8KB x2
  const int bh = blockIdx.y;   // 64
  const int qt = blockIdx.x;   // 16
  const int t = threadIdx.x;
  const int w = t >> 6, l = t & 63;
  const int lq = l & 31, hh = l >> 5;
  const int xr = lq & 7;
  const int qrow = qt * 128 + w * 32 + lq;

  const short* qp = q + ((size_t)(bh * 2048 + qrow)) * 64 + hh * 8;
  bf16x8 qf[4];
#pragma unroll
  for (int db = 0; db < 4; ++db) qf[db] = *reinterpret_cast<const bf16x8*>(qp + db * 16);

  // staging: each wave stages granules [w*128, w*128+128)
  const int gg0 = w * 128 + l, gg1 = gg0 + 64;
  const int u0 = gg0 ^ ((gg0 >> 3) & 7);
  const int u1 = gg1 ^ ((gg1 >> 3) & 7);
  const short* kh = k + (size_t)bh * 2048 * 64;
  const short* vh = vt + (size_t)bh * 64 * 2048;
  const short* ksrc0 = kh + u0 * 8;
  const short* ksrc1 = kh + u1 * 8;
  const short* vsrc0 = vh + (gg0 >> 3) * 2048 + (u0 & 7) * 8;
  const short* vsrc1 = vh + (gg1 >> 3) * 2048 + (u1 & 7) * 8;

  int koff[2][4], voff[2][4];
#pragma unroll
  for (int ks = 0; ks < 2; ++ks)
#pragma unroll
    for (int db = 0; db < 4; ++db)
      koff[ks][db] = ((ks * 32 + lq) * 8 + ((db * 2 + hh) ^ xr)) * 8;
#pragma unroll
  for (int dt = 0; dt < 2; ++dt)
#pragma unroll
    for (int kg = 0; kg < 4; ++kg)
      voff[dt][kg] = ((dt * 32 + lq) * 8 + ((kg * 2 + hh) ^ xr)) * 8;

  f32x16 oa0 = zero16(), oa1 = zero16();
  float mr = -1e30f, lr = 0.f;  // lr is a per-half partial; combined at the end

  gld_lds16(ksrc0, &Ks[0][gg0 * 8]);
  gld_lds16(ksrc1, &Ks[0][gg1 * 8]);
  gld_lds16(vsrc0, &Vs[0][gg0 * 8]);
  gld_lds16(vsrc1, &Vs[0][gg1 * 8]);
  __syncthreads();

  int cur = 0;
  for (int kt = 0; kt < 32; ++kt) {
    const int kn = (kt + 1) & 31;
    const int nb = cur ^ 1;
    gld_lds16(ksrc0 + kn * 4096, &Ks[nb][gg0 * 8]);
    gld_lds16(ksrc1 + kn * 4096, &Ks[nb][gg1 * 8]);
    gld_lds16(vsrc0 + kn * 64, &Vs[nb][gg0 * 8]);
    gld_lds16(vsrc1 + kn * 64, &Vs[nb][gg1 * 8]);

    const short* kb_ = Ks[cur];
    const short* vb_ = Vs[cur];
    f32x16 s0 = zero16(), s1 = zero16();
    __builtin_amdgcn_s_setprio(1);
#pragma unroll
    for (int db = 0; db < 4; ++db) {
      bf16x8 kf = *reinterpret_cast<const bf16x8*>(kb_ + koff[0][db]);
      s0 = __builtin_amdgcn_mfma_f32_32x32x16_bf16(kf, qf[db], s0, 0, 0, 0);
    }
#pragma unroll
    for (int db = 0; db < 4; ++db) {
      bf16x8 kf = *reinterpret_cast<const bf16x8*>(kb_ + koff[1][db]);
      s1 = __builtin_amdgcn_mfma_f32_32x32x16_bf16(kf, qf[db], s1, 0, 0, 0);
    }
    __builtin_amdgcn_s_setprio(0);
    // tile max: v_max3 tree over 32 regs, then cross-half permlane
    float m8[8];
#pragma unroll
    for (int i = 0; i < 8; ++i)
      m8[i] = fmax3(fmaxf(s0[i], s0[i + 8]), s1[i], s1[i + 8]);
    float t0 = fmax3(m8[0], m8[1], m8[2]);
    float t1 = fmax3(m8[3], m8[4], m8[5]);
    float tm = fmax3(fmax3(m8[6], m8[7], t0), t1, -1e30f);
    tm = xhalf_max(tm);
    // defer-max rescale (log2 domain, THR=8 => P <= 256)
    if (!__all(tm <= mr + 8.f)) {
      const float mn = fmaxf(mr, tm);
      const float corr = EXP2(mr - mn);
      lr *= corr;
#pragma unroll
      for (int r = 0; r < 16; ++r) { oa0[r] *= corr; oa1[r] *= corr; }
      mr = mn;
    }
#pragma unroll
    for (int r = 0; r < 16; ++r) {
      s0[r] = EXP2(s0[r] - mr);
      s1[r] = EXP2(s1[r] - mr);
    }
    float a8[8];
#pragma unroll
    for (int i = 0; i < 8; ++i)
      a8[i] = (s0[i] + s0[i + 8]) + (s1[i] + s1[i + 8]);
    lr += ((a8[0] + a8[4]) + (a8[1] + a8[5])) + ((a8[2] + a8[6]) + (a8[3] + a8[7]));
    // PV
    __builtin_amdgcn_s_setprio(1);
#pragma unroll
    for (int kg = 0; kg < 4; ++kg) {
      const f32x16& sv = (kg & 2) ? s1 : s0;
      const int b0 = (kg & 1) * 8;
      unsigned w0 = cvtpk_bf16(sv[b0 + 0], sv[b0 + 1]);
      unsigned w1 = cvtpk_bf16(sv[b0 + 2], sv[b0 + 3]);
      unsigned w2 = cvtpk_bf16(sv[b0 + 4], sv[b0 + 5]);
      unsigned w3 = cvtpk_bf16(sv[b0 + 6], sv[b0 + 7]);
      plane32_swap(w0, w2);
      plane32_swap(w1, w3);
      u32x4 pw = {w0, w1, w2, w3};
      bf16x8 pf = *reinterpret_cast<bf16x8*>(&pw);
      bf16x8 vf0 = *reinterpret_cast<const bf16x8*>(vb_ + voff[0][kg]);
      oa0 = __builtin_amdgcn_mfma_f32_32x32x16_bf16(vf0, pf, oa0, 0, 0, 0);
      bf16x8 vf1 = *reinterpret_cast<const bf16x8*>(vb_ + voff[1][kg]);
      oa1 = __builtin_amdgcn_mfma_f32_32x32x16_bf16(vf1, pf, oa1, 0, 0, 0);
    }
    __builtin_amdgcn_s_setprio(0);
    __syncthreads();
    cur = nb;
  }
  const float lt = xhalf_sum(lr);  // combine per-half partials once
  const float inv = 1.0f / lt;
  const int b = bh >> 4, hd = bh & 15;
  _Float16* ob = o + ((size_t)(b * 2048 + qrow)) * 1024 + hd * 64;
#pragma unroll
  for (int r2 = 0; r2 < 16; ++r2) {
    const int d0 = (r2 & 3) + 8 * (r2 >> 2) + 4 * hh;  // 32x32 C layout
    ob[d0] = (_Float16)(oa0[r2] * inv);
    ob[d0 + 32] = (_Float16)(oa1[r2] * inv);
  }
}

// ---------- launch ----------
extern "C" void kernel_launch(void* const* d_in, const int* in_sizes, int n_in,
                              void* d_out, int out_size, void* d_ws, size_t ws_size,
                              hipStream_t stream) {
  const float* x = (const float*)d_in[0];
  const float* w_in = (const float*)d_in[1];
  const float* b_in = (const float*)d_in[2];
  const float* w_norm = (const float*)d_in[3];
  const float* w_out = (const float*)d_in[4];
  const float* b_out = (const float*)d_in[5];
  float* out = (float*)d_out;
  char* ws = (char*)d_ws;
  short* xn = (short*)(ws);                       // 16 MB [8192][1024] bf16
  short* win_b = (short*)(ws + 16777216);         // 6 MB  [3072][1024] bf16
  _Float16* wout_h = (_Float16*)(ws + 23068672);  // 2 MB  [1024][1024] f16
  short* qb = (short*)(ws + 25165824);            // 16 MB [64][2048][64] bf16
  short* kb = (short*)(ws + 41943040);            // 16 MB
  short* vb = (short*)(ws + 58720256);            // 16 MB
  short* vt = (short*)(ws + 75497472);            // 16 MB [64][64][2048]
  _Float16* ob = (_Float16*)vb;                   // alias: v dead after transpose

  k_cast_bf<<<3072, 256, 0, stream>>>(w_in, win_b, 786432);
  k_cast_f16<<<1024, 256, 0, stream>>>(w_out, wout_h, 262144);
  k_rmsnorm<<<8192, 256, 0, stream>>>(x, w_norm, xn);
  k_gemm_qkv<<<dim3(24, 64), 256, 0, stream>>>(xn, win_b, b_in, qb, kb, vb);
  k_transpose_v<<<dim3(32, 64), 256, 0, stream>>>(vb, vt);
  k_attn<<<dim3(16, 64), 256, 0, stream>>>(qb, kb, vt, ob);
  k_gemm_out<<<dim3(8, 64), 256, 0, stream>>>(ob, wout_h, b_out, out);
}

// Round 6
// 231.491 us; speedup vs baseline: 1.0451x; 1.0451x over previous
//
#include <hip/hip_runtime.h>
#include <stdint.h>

typedef short bf16x4 __attribute__((ext_vector_type(4)));
typedef short bf16x8 __attribute__((ext_vector_type(8)));
typedef _Float16 f16x8 __attribute__((ext_vector_type(8)));
typedef float f32x4 __attribute__((ext_vector_type(4)));
typedef float f32x16 __attribute__((ext_vector_type(16)));
typedef unsigned int u32x4 __attribute__((ext_vector_type(4)));
typedef unsigned int u32x2 __attribute__((ext_vector_type(2)));

#if __has_builtin(__builtin_amdgcn_exp2f)
#define EXP2 __builtin_amdgcn_exp2f
#else
#define EXP2 exp2f
#endif

// ---------- helpers ----------
__device__ __forceinline__ short f2bf(float f) {  // RNE f32->bf16 (finite inputs)
  union { float f; uint32_t u; } v; v.f = f;
  uint32_t r = (v.u + 0x7fffu + ((v.u >> 16) & 1u)) >> 16;
  return (short)(uint16_t)r;
}

__device__ __forceinline__ unsigned cvtpk_bf16(float lo, float hi) {
  unsigned r;
  asm("v_cvt_pk_bf16_f32 %0, %1, %2" : "=v"(r) : "v"(lo), "v"(hi));
  return r;
}

// v_permlane32_swap_b32 via the BUILTIN (hazard-safe; round-5 verified).
#if __has_builtin(__builtin_amdgcn_permlane32_swap)
__device__ __forceinline__ void plane32_swap(unsigned& a, unsigned& b) {
  u32x2 r = __builtin_amdgcn_permlane32_swap(a, b, false, false);
  a = r[0]; b = r[1];
}
__device__ __forceinline__ float xhalf_max(float x) {
  unsigned xu = __builtin_bit_cast(unsigned, x);
  u32x2 r = __builtin_amdgcn_permlane32_swap(xu, xu, false, false);
  return fmaxf(__builtin_bit_cast(float, r[0]), __builtin_bit_cast(float, r[1]));
}
__device__ __forceinline__ float xhalf_sum(float x) {
  unsigned xu = __builtin_bit_cast(unsigned, x);
  u32x2 r = __builtin_amdgcn_permlane32_swap(xu, xu, false, false);
  return __builtin_bit_cast(float, r[0]) + __builtin_bit_cast(float, r[1]);
}
#else
__device__ __forceinline__ void plane32_swap(unsigned& a, unsigned& b) {
  asm("s_nop 1\n\tv_permlane32_swap_b32 %0, %1" : "+v"(a), "+v"(b));
}
__device__ __forceinline__ float xhalf_max(float x) { return fmaxf(x, __shfl_xor(x, 32, 64)); }
__device__ __forceinline__ float xhalf_sum(float x) { return x + __shfl_xor(x, 32, 64); }
#endif

__device__ __forceinline__ float fmax3(float a, float b, float c) {
  return fmaxf(fmaxf(a, b), c);  // clang fuses to v_max3_f32
}

__device__ __forceinline__ float tmax16(const f32x16& s) {
  float a0 = fmax3(s[0], s[1], s[2]);
  float a1 = fmax3(s[3], s[4], s[5]);
  float a2 = fmax3(s[6], s[7], s[8]);
  float a3 = fmax3(s[9], s[10], s[11]);
  float a4 = fmax3(s[12], s[13], s[14]);
  float b0 = fmax3(a0, a1, s[15]);
  float b1 = fmax3(a2, a3, a4);
  return fmaxf(b0, b1);
}
__device__ __forceinline__ float tsum16(const f32x16& s) {
  float a0 = (s[0] + s[1]) + (s[2] + s[3]);
  float a1 = (s[4] + s[5]) + (s[6] + s[7]);
  float a2 = (s[8] + s[9]) + (s[10] + s[11]);
  float a3 = (s[12] + s[13]) + (s[14] + s[15]);
  return (a0 + a1) + (a2 + a3);
}

__device__ __forceinline__ f32x16 zero16() {
  f32x16 z;
#pragma unroll
  for (int i = 0; i < 16; ++i) z[i] = 0.f;
  return z;
}

__device__ __forceinline__ void gld_lds16(const void* g, void* l) {
  __builtin_amdgcn_global_load_lds(
      (__attribute__((address_space(1))) const void*)g,
      (__attribute__((address_space(3))) void*)l, 16, 0, 0);
}

// ---------- RMSNorm + cast to bf16 ----------
__global__ __launch_bounds__(256) void k_rmsnorm(const float* __restrict__ x,
                                                 const float* __restrict__ wn,
                                                 short* __restrict__ xn) {
  const int row = blockIdx.x;      // 8192 rows
  const int t = threadIdx.x;       // 256 threads, 4 floats each
  const float4 v = reinterpret_cast<const float4*>(x + (size_t)row * 1024)[t];
  float ss = v.x * v.x + v.y * v.y + v.z * v.z + v.w * v.w;
#pragma unroll
  for (int m = 32; m >= 1; m >>= 1) ss += __shfl_xor(ss, m, 64);
  __shared__ float red[4];
  if ((t & 63) == 0) red[t >> 6] = ss;
  __syncthreads();
  const float tot = red[0] + red[1] + red[2] + red[3];
  const float rr = rsqrtf(tot * (1.0f / 1024.0f) + 1e-5f);
  const float4 g = reinterpret_cast<const float4*>(wn)[t];
  bf16x4 o;
  o[0] = f2bf(v.x * rr * g.x);
  o[1] = f2bf(v.y * rr * g.y);
  o[2] = f2bf(v.z * rr * g.z);
  o[3] = f2bf(v.w * rr * g.w);
  reinterpret_cast<bf16x4*>(xn + (size_t)row * 1024)[t] = o;
}

// ---------- casts ----------
__global__ __launch_bounds__(256) void k_cast_bf(const float* __restrict__ in,
                                                 short* __restrict__ out, int n4) {
  int i = blockIdx.x * 256 + threadIdx.x;
  if (i >= n4) return;
  float4 v = reinterpret_cast<const float4*>(in)[i];
  bf16x4 o;
  o[0] = f2bf(v.x); o[1] = f2bf(v.y); o[2] = f2bf(v.z); o[3] = f2bf(v.w);
  reinterpret_cast<bf16x4*>(out)[i] = o;
}

__global__ __launch_bounds__(256) void k_cast_f16(const float* __restrict__ in,
                                                  _Float16* __restrict__ out, int n4) {
  int i = blockIdx.x * 256 + threadIdx.x;
  if (i >= n4) return;
  float4 v = reinterpret_cast<const float4*>(in)[i];
  _Float16 o[4] = {(_Float16)v.x, (_Float16)v.y, (_Float16)v.z, (_Float16)v.w};
  reinterpret_cast<ulong1*>(out)[i] = *reinterpret_cast<ulong1*>(o);
}

// ---------- QKV GEMM (bf16, m97 structure, 128x128xBK32, T1 XCD swizzle) ----------
__global__ __launch_bounds__(256) void k_gemm_qkv(const short* __restrict__ A,
                                                  const short* __restrict__ B,
                                                  const float* __restrict__ bias,
                                                  short* __restrict__ qb,
                                                  short* __restrict__ kb,
                                                  short* __restrict__ vb) {
  __shared__ __align__(16) short As[128 * 32];
  __shared__ __align__(16) short Bs[128 * 32];
  const int t = threadIdx.x;
  // T1: XCD-aware remap (nwg = 24*64 = 1536, 1536%8==0)
  const int orig = blockIdx.y * 24 + blockIdx.x;
  const int swz = (orig & 7) * 192 + (orig >> 3);
  const long bn0 = (long)(swz % 24) * 128;
  const long bm0 = (long)(swz / 24) * 128;
  const int w = t >> 6, l = t & 63;
  const int wr = (w >> 1) * 64, wc = (w & 1) * 64;
  const int lm = l & 15, h = l >> 4;
  f32x4 acc[4][4];
#pragma unroll
  for (int i = 0; i < 4; ++i)
#pragma unroll
    for (int j = 0; j < 4; ++j) acc[i][j] = (f32x4){0.f, 0.f, 0.f, 0.f};
  const int srow = t >> 2, scol = (t & 3) * 8;
  const short* Ag = A + (bm0 + srow) * 1024 + scol;
  const short* Bg = B + (bn0 + srow) * 1024 + scol;
  short* AsP = As + t * 8;
  short* BsP = Bs + t * 8;
  for (int kt = 0; kt < 32; ++kt) {
    const int k0 = kt << 5;
    gld_lds16(Ag + k0, AsP);
    gld_lds16(Ag + k0 + 64 * 1024, AsP + 2048);
    gld_lds16(Bg + k0, BsP);
    gld_lds16(Bg + k0 + 64 * 1024, BsP + 2048);
    __syncthreads();
    bf16x8 af[4], bfr[4];
#pragma unroll
    for (int mi = 0; mi < 4; ++mi)
      af[mi] = *reinterpret_cast<const bf16x8*>(As + (wr + mi * 16 + lm) * 32 + h * 8);
#pragma unroll
    for (int ni = 0; ni < 4; ++ni)
      bfr[ni] = *reinterpret_cast<const bf16x8*>(Bs + (wc + ni * 16 + lm) * 32 + h * 8);
    __builtin_amdgcn_s_setprio(1);
#pragma unroll
    for (int mi = 0; mi < 4; ++mi)
#pragma unroll
      for (int ni = 0; ni < 4; ++ni)
        acc[mi][ni] = __builtin_amdgcn_mfma_f32_16x16x32_bf16(af[mi], bfr[ni], acc[mi][ni], 0, 0, 0);
    __builtin_amdgcn_s_setprio(0);
    __syncthreads();
  }
#pragma unroll
  for (int ni = 0; ni < 4; ++ni) {
    const int ncol = (int)bn0 + wc + ni * 16 + lm;
    const float bv = bias[ncol];
    const int which = ncol >> 10;
    const int e = ncol & 1023;
#pragma unroll
    for (int mi = 0; mi < 4; ++mi) {
#pragma unroll
      for (int r = 0; r < 4; ++r) {
        const long mrow = bm0 + wr + mi * 16 + h * 4 + r;
        const float val = acc[mi][ni][r] + bv;
        const long off = (((mrow >> 11) * 16 + (e >> 6)) * 2048 + (mrow & 2047)) * 64 + (e & 63);
        if (which == 0) qb[off] = f2bf(val * 0.18033688011112042f);  // 0.125*log2(e)
        else if (which == 1) kb[off] = f2bf(val);
        else vb[off] = f2bf(val);
      }
    }
  }
}

// ---------- out-proj GEMM (fp16 inputs for precision, fp32 out) ----------
__global__ __launch_bounds__(256) void k_gemm_out(const _Float16* __restrict__ A,
                                                  const _Float16* __restrict__ B,
                                                  const float* __restrict__ bias,
                                                  float* __restrict__ outp) {
  __shared__ __align__(16) _Float16 As[128 * 32];
  __shared__ __align__(16) _Float16 Bs[128 * 32];
  const int t = threadIdx.x;
  // T1: nwg = 8*64 = 512, 512%8==0
  const int orig = blockIdx.y * 8 + blockIdx.x;
  const int swz = (orig & 7) * 64 + (orig >> 3);
  const long bn0 = (long)(swz % 8) * 128;
  const long bm0 = (long)(swz / 8) * 128;
  const int w = t >> 6, l = t & 63;
  const int wr = (w >> 1) * 64, wc = (w & 1) * 64;
  const int lm = l & 15, h = l >> 4;
  f32x4 acc[4][4];
#pragma unroll
  for (int i = 0; i < 4; ++i)
#pragma unroll
    for (int j = 0; j < 4; ++j) acc[i][j] = (f32x4){0.f, 0.f, 0.f, 0.f};
  const int srow = t >> 2, scol = (t & 3) * 8;
  const _Float16* Ag = A + (bm0 + srow) * 1024 + scol;
  const _Float16* Bg = B + (bn0 + srow) * 1024 + scol;
  _Float16* AsP = As + t * 8;
  _Float16* BsP = Bs + t * 8;
  for (int kt = 0; kt < 32; ++kt) {
    const int k0 = kt << 5;
    gld_lds16(Ag + k0, AsP);
    gld_lds16(Ag + k0 + 64 * 1024, AsP + 2048);
    gld_lds16(Bg + k0, BsP);
    gld_lds16(Bg + k0 + 64 * 1024, BsP + 2048);
    __syncthreads();
    f16x8 af[4], bfr[4];
#pragma unroll
    for (int mi = 0; mi < 4; ++mi)
      af[mi] = *reinterpret_cast<const f16x8*>(As + (wr + mi * 16 + lm) * 32 + h * 8);
#pragma unroll
    for (int ni = 0; ni < 4; ++ni)
      bfr[ni] = *reinterpret_cast<const f16x8*>(Bs + (wc + ni * 16 + lm) * 32 + h * 8);
    __builtin_amdgcn_s_setprio(1);
#pragma unroll
    for (int mi = 0; mi < 4; ++mi)
#pragma unroll
      for (int ni = 0; ni < 4; ++ni)
        acc[mi][ni] = __builtin_amdgcn_mfma_f32_16x16x32_f16(af[mi], bfr[ni], acc[mi][ni], 0, 0, 0);
    __builtin_amdgcn_s_setprio(0);
    __syncthreads();
  }
#pragma unroll
  for (int ni = 0; ni < 4; ++ni) {
    const int ncol = (int)bn0 + wc + ni * 16 + lm;
    const float bv = bias[ncol];
#pragma unroll
    for (int mi = 0; mi < 4; ++mi) {
#pragma unroll
      for (int r = 0; r < 4; ++r) {
        const long mrow = bm0 + wr + mi * 16 + h * 4 + r;
        outp[mrow * 1024 + ncol] = acc[mi][ni][r] + bv;
      }
    }
  }
}

// ---------- V transpose: v[BH][S][64] -> vT[BH][64][S] ----------
__global__ __launch_bounds__(256) void k_transpose_v(const short* __restrict__ v,
                                                     short* __restrict__ vt) {
  __shared__ short tile[64][72];
  const int bh = blockIdx.y, st = blockIdx.x;  // 32 s-tiles of 64
  const int t = threadIdx.x;
  const int r = t >> 2, c0 = (t & 3) * 16;
  const short* src = v + ((size_t)(bh * 2048 + st * 64 + r)) * 64 + c0;
  bf16x8 a = *reinterpret_cast<const bf16x8*>(src);
  bf16x8 b = *reinterpret_cast<const bf16x8*>(src + 8);
#pragma unroll
  for (int j = 0; j < 8; ++j) tile[r][c0 + j] = a[j];
#pragma unroll
  for (int j = 0; j < 8; ++j) tile[r][c0 + 8 + j] = b[j];
  __syncthreads();
  __align__(16) short tmp[16];
#pragma unroll
  for (int j = 0; j < 16; ++j) tmp[j] = tile[c0 + j][r];
  short* dst = vt + ((size_t)(bh * 64 + r)) * 2048 + st * 64 + c0;
  *reinterpret_cast<bf16x8*>(dst) = *reinterpret_cast<const bf16x8*>(tmp);
  *reinterpret_cast<bf16x8*>(dst + 8) = *reinterpret_cast<const bf16x8*>(tmp + 8);
}

// ---------- flash attention v4: 64 q-rows per wave ----------
// 4 waves/block, 256 q-rows/block, KBLK=32. Each wave computes TWO 32-q-row
// column tiles (qh=0,1) sharing every K/V fragment: 8 ds_read_b128 feed
// 16 MFMAs per iter (2x the read amortization of v3), and total blocks halve
// (512 -> 2/CU) so per-CU LDS traffic halves. Per-lane state: two q-rows
// (qh*32+lq), each with its own (mr,lr) per-half partials.
__global__ __launch_bounds__(256, 2) void k_attn(const short* __restrict__ q,
                                                 const short* __restrict__ k,
                                                 const short* __restrict__ vt,
                                                 _Float16* __restrict__ o) {
  __shared__ __align__(16) short Ks[2][2048];  // 32 keys x 64 d = 4KB x2
  __shared__ __align__(16) short Vs[2][2048];  // 64 d x 32 keys = 4KB x2
  const int bh = blockIdx.y;   // 64
  const int qt = blockIdx.x;   // 8
  const int t = threadIdx.x;
  const int w = t >> 6, l = t & 63;
  const int lq = l & 31, hh = l >> 5;
  const int xr = lq & 7;
  const int qbase = qt * 256 + w * 64;

  // Q fragments: qf[qh][db] = Q[qbase+qh*32+lq][db*16 + hh*8 .. +8]
  bf16x8 qf[2][4];
#pragma unroll
  for (int qh = 0; qh < 2; ++qh) {
    const short* qp = q + ((size_t)(bh * 2048 + qbase + qh * 32 + lq)) * 64 + hh * 8;
#pragma unroll
    for (int db = 0; db < 4; ++db)
      qf[qh][db] = *reinterpret_cast<const bf16x8*>(qp + db * 16);
  }

  // staging: 256 granules (16B) per tensor per tile, 1 per thread
  const int gg = t;
  const int uK = gg ^ ((gg >> 3) & 7);            // K: row=gg>>3 (key), col=gg&7 (8/row)
  const int vrow = gg >> 2;                       // V: row=d (4 granules/row)
  const int vcol = (gg & 3) ^ (vrow & 3);
  const short* kh = k + (size_t)bh * 2048 * 64;
  const short* vh = vt + (size_t)bh * 64 * 2048;
  const short* ksrc = kh + uK * 8;                // + kt*2048 per iter
  const short* vsrc = vh + vrow * 2048 + vcol * 8;  // + kt*32 per iter

  // swizzled LDS read offsets (shorts)
  int koff[4], voff[2][2];
#pragma unroll
  for (int db = 0; db < 4; ++db)
    koff[db] = (lq * 8 + ((db * 2 + hh) ^ xr)) * 8;
#pragma unroll
  for (int dt = 0; dt < 2; ++dt)
#pragma unroll
    for (int kg = 0; kg < 2; ++kg)
      voff[dt][kg] = ((dt * 32 + lq) * 4 + ((kg * 2 + hh) ^ (lq & 3))) * 8;

  f32x16 oa00 = zero16(), oa01 = zero16();  // qh=0: dt=0,1
  f32x16 oa10 = zero16(), oa11 = zero16();  // qh=1: dt=0,1
  float mr0 = -1e30f, mr1 = -1e30f, lr0 = 0.f, lr1 = 0.f;

  gld_lds16(ksrc, &Ks[0][gg * 8]);
  gld_lds16(vsrc, &Vs[0][gg * 8]);
  __syncthreads();

  int cur = 0;
  for (int kt = 0; kt < 64; ++kt) {
    const int kn = (kt + 1) & 63;
    const int nb = cur ^ 1;
    gld_lds16(ksrc + kn * 2048, &Ks[nb][gg * 8]);
    gld_lds16(vsrc + kn * 32, &Vs[nb][gg * 8]);

    const short* kb_ = Ks[cur];
    const short* vb_ = Vs[cur];
    f32x16 s0 = zero16(), s1 = zero16();  // qh=0, qh=1 (32 keys x 32 q each)
    __builtin_amdgcn_s_setprio(1);
#pragma unroll
    for (int db = 0; db < 4; ++db) {
      bf16x8 kf = *reinterpret_cast<const bf16x8*>(kb_ + koff[db]);
      s0 = __builtin_amdgcn_mfma_f32_32x32x16_bf16(kf, qf[0][db], s0, 0, 0, 0);
      s1 = __builtin_amdgcn_mfma_f32_32x32x16_bf16(kf, qf[1][db], s1, 0, 0, 0);
    }
    __builtin_amdgcn_s_setprio(0);
    // per-q-row tile max (s0: row qh0, s1: row qh1)
    float tm0 = xhalf_max(tmax16(s0));
    float tm1 = xhalf_max(tmax16(s1));
    // defer-max rescale (log2 domain, THR=8 => P <= 256)
    if (!__all((tm0 <= mr0 + 8.f) && (tm1 <= mr1 + 8.f))) {
      const float mn0 = fmaxf(mr0, tm0), mn1 = fmaxf(mr1, tm1);
      const float c0 = EXP2(mr0 - mn0), c1 = EXP2(mr1 - mn1);
      lr0 *= c0; lr1 *= c1;
#pragma unroll
      for (int r = 0; r < 16; ++r) {
        oa00[r] *= c0; oa01[r] *= c0;
        oa10[r] *= c1; oa11[r] *= c1;
      }
      mr0 = mn0; mr1 = mn1;
    }
#pragma unroll
    for (int r = 0; r < 16; ++r) {
      s0[r] = EXP2(s0[r] - mr0);
      s1[r] = EXP2(s1[r] - mr1);
    }
    lr0 += tsum16(s0);  // per-half partial; combined once at the end
    lr1 += tsum16(s1);
    // PV: per 16-key group build P-frags for both qh; V-frags reused across qh
    __builtin_amdgcn_s_setprio(1);
#pragma unroll
    for (int kg = 0; kg < 2; ++kg) {
      const int b0 = kg * 8;
      unsigned p00 = cvtpk_bf16(s0[b0 + 0], s0[b0 + 1]);
      unsigned p01 = cvtpk_bf16(s0[b0 + 2], s0[b0 + 3]);
      unsigned p02 = cvtpk_bf16(s0[b0 + 4], s0[b0 + 5]);
      unsigned p03 = cvtpk_bf16(s0[b0 + 6], s0[b0 + 7]);
      plane32_swap(p00, p02);
      plane32_swap(p01, p03);
      u32x4 pw0 = {p00, p01, p02, p03};
      bf16x8 pf0 = *reinterpret_cast<bf16x8*>(&pw0);
      unsigned p10 = cvtpk_bf16(s1[b0 + 0], s1[b0 + 1]);
      unsigned p11 = cvtpk_bf16(s1[b0 + 2], s1[b0 + 3]);
      unsigned p12 = cvtpk_bf16(s1[b0 + 4], s1[b0 + 5]);
      unsigned p13 = cvtpk_bf16(s1[b0 + 6], s1[b0 + 7]);
      plane32_swap(p10, p12);
      plane32_swap(p11, p13);
      u32x4 pw1 = {p10, p11, p12, p13};
      bf16x8 pf1 = *reinterpret_cast<bf16x8*>(&pw1);
      bf16x8 vf0 = *reinterpret_cast<const bf16x8*>(vb_ + voff[0][kg]);
      oa00 = __builtin_amdgcn_mfma_f32_32x32x16_bf16(vf0, pf0, oa00, 0, 0, 0);
      oa10 = __builtin_amdgcn_mfma_f32_32x32x16_bf16(vf0, pf1, oa10, 0, 0, 0);
      bf16x8 vf1 = *reinterpret_cast<const bf16x8*>(vb_ + voff[1][kg]);
      oa01 = __builtin_amdgcn_mfma_f32_32x32x16_bf16(vf1, pf0, oa01, 0, 0, 0);
      oa11 = __builtin_amdgcn_mfma_f32_32x32x16_bf16(vf1, pf1, oa11, 0, 0, 0);
    }
    __builtin_amdgcn_s_setprio(0);
    __syncthreads();
    cur = nb;
  }
  const float inv0 = 1.0f / xhalf_sum(lr0);
  const float inv1 = 1.0f / xhalf_sum(lr1);
  const int b = bh >> 4, hd = bh & 15;
  _Float16* ob0 = o + ((size_t)(b * 2048 + qbase + lq)) * 1024 + hd * 64;
  _Float16* ob1 = ob0 + 32 * 1024;
#pragma unroll
  for (int r2 = 0; r2 < 16; ++r2) {
    const int d0 = (r2 & 3) + 8 * (r2 >> 2) + 4 * hh;  // 32x32 C layout
    ob0[d0] = (_Float16)(oa00[r2] * inv0);
    ob0[d0 + 32] = (_Float16)(oa01[r2] * inv0);
    ob1[d0] = (_Float16)(oa10[r2] * inv1);
    ob1[d0 + 32] = (_Float16)(oa11[r2] * inv1);
  }
}

// ---------- launch ----------
extern "C" void kernel_launch(void* const* d_in, const int* in_sizes, int n_in,
                              void* d_out, int out_size, void* d_ws, size_t ws_size,
                              hipStream_t stream) {
  const float* x = (const float*)d_in[0];
  const float* w_in = (const float*)d_in[1];
  const float* b_in = (const float*)d_in[2];
  const float* w_norm = (const float*)d_in[3];
  const float* w_out = (const float*)d_in[4];
  const float* b_out = (const float*)d_in[5];
  float* out = (float*)d_out;
  char* ws = (char*)d_ws;
  short* xn = (short*)(ws);                       // 16 MB [8192][1024] bf16
  short* win_b = (short*)(ws + 16777216);         // 6 MB  [3072][1024] bf16
  _Float16* wout_h = (_Float16*)(ws + 23068672);  // 2 MB  [1024][1024] f16
  short* qb = (short*)(ws + 25165824);            // 16 MB [64][2048][64] bf16
  short* kb = (short*)(ws + 41943040);            // 16 MB
  short* vb = (short*)(ws + 58720256);            // 16 MB
  short* vt = (short*)(ws + 75497472);            // 16 MB [64][64][2048]
  _Float16* ob = (_Float16*)vb;                   // alias: v dead after transpose

  k_cast_bf<<<3072, 256, 0, stream>>>(w_in, win_b, 786432);
  k_cast_f16<<<1024, 256, 0, stream>>>(w_out, wout_h, 262144);
  k_rmsnorm<<<8192, 256, 0, stream>>>(x, w_norm, xn);
  k_gemm_qkv<<<dim3(24, 64), 256, 0, stream>>>(xn, win_b, b_in, qb, kb, vb);
  k_transpose_v<<<dim3(32, 64), 256, 0, stream>>>(vb, vt);
  k_attn<<<dim3(8, 64), 256, 0, stream>>>(qb, kb, vt, ob);
  k_gemm_out<<<dim3(8, 64), 256, 0, stream>>>(ob, wout_h, b_out, out);
}

// Round 7
// 227.364 us; speedup vs baseline: 1.0641x; 1.0182x over previous
//
#include <hip/hip_runtime.h>
#include <stdint.h>

typedef short bf16x4 __attribute__((ext_vector_type(4)));
typedef short bf16x8 __attribute__((ext_vector_type(8)));
typedef _Float16 f16x8 __attribute__((ext_vector_type(8)));
typedef float f32x4 __attribute__((ext_vector_type(4)));
typedef float f32x16 __attribute__((ext_vector_type(16)));
typedef unsigned int u32x4 __attribute__((ext_vector_type(4)));
typedef unsigned int u32x2 __attribute__((ext_vector_type(2)));

#if __has_builtin(__builtin_amdgcn_exp2f)
#define EXP2 __builtin_amdgcn_exp2f
#else
#define EXP2 exp2f
#endif

// ---------- helpers ----------
__device__ __forceinline__ short f2bf(float f) {  // RNE f32->bf16 (finite inputs)
  union { float f; uint32_t u; } v; v.f = f;
  uint32_t r = (v.u + 0x7fffu + ((v.u >> 16) & 1u)) >> 16;
  return (short)(uint16_t)r;
}

__device__ __forceinline__ unsigned cvtpk_bf16(float lo, float hi) {
  unsigned r;
  asm("v_cvt_pk_bf16_f32 %0, %1, %2" : "=v"(r) : "v"(lo), "v"(hi));
  return r;
}

// v_permlane32_swap_b32 via the BUILTIN (hazard-safe; round-5 verified).
#if __has_builtin(__builtin_amdgcn_permlane32_swap)
__device__ __forceinline__ void plane32_swap(unsigned& a, unsigned& b) {
  u32x2 r = __builtin_amdgcn_permlane32_swap(a, b, false, false);
  a = r[0]; b = r[1];
}
__device__ __forceinline__ float xhalf_max(float x) {
  unsigned xu = __builtin_bit_cast(unsigned, x);
  u32x2 r = __builtin_amdgcn_permlane32_swap(xu, xu, false, false);
  return fmaxf(__builtin_bit_cast(float, r[0]), __builtin_bit_cast(float, r[1]));
}
__device__ __forceinline__ float xhalf_sum(float x) {
  unsigned xu = __builtin_bit_cast(unsigned, x);
  u32x2 r = __builtin_amdgcn_permlane32_swap(xu, xu, false, false);
  return __builtin_bit_cast(float, r[0]) + __builtin_bit_cast(float, r[1]);
}
#else
__device__ __forceinline__ void plane32_swap(unsigned& a, unsigned& b) {
  asm("s_nop 1\n\tv_permlane32_swap_b32 %0, %1" : "+v"(a), "+v"(b));
}
__device__ __forceinline__ float xhalf_max(float x) { return fmaxf(x, __shfl_xor(x, 32, 64)); }
__device__ __forceinline__ float xhalf_sum(float x) { return x + __shfl_xor(x, 32, 64); }
#endif

__device__ __forceinline__ float fmax3(float a, float b, float c) {
  return fmaxf(fmaxf(a, b), c);  // clang fuses to v_max3_f32
}

__device__ __forceinline__ float tmax16(const f32x16& s) {
  float a0 = fmax3(s[0], s[1], s[2]);
  float a1 = fmax3(s[3], s[4], s[5]);
  float a2 = fmax3(s[6], s[7], s[8]);
  float a3 = fmax3(s[9], s[10], s[11]);
  float a4 = fmax3(s[12], s[13], s[14]);
  float b0 = fmax3(a0, a1, s[15]);
  float b1 = fmax3(a2, a3, a4);
  return fmaxf(b0, b1);
}
__device__ __forceinline__ float tsum16(const f32x16& s) {
  float a0 = (s[0] + s[1]) + (s[2] + s[3]);
  float a1 = (s[4] + s[5]) + (s[6] + s[7]);
  float a2 = (s[8] + s[9]) + (s[10] + s[11]);
  float a3 = (s[12] + s[13]) + (s[14] + s[15]);
  return (a0 + a1) + (a2 + a3);
}

__device__ __forceinline__ f32x16 zero16() {
  f32x16 z;
#pragma unroll
  for (int i = 0; i < 16; ++i) z[i] = 0.f;
  return z;
}

__device__ __forceinline__ void gld_lds16(const void* g, void* l) {
  __builtin_amdgcn_global_load_lds(
      (__attribute__((address_space(1))) const void*)g,
      (__attribute__((address_space(3))) void*)l, 16, 0, 0);
}

// ---------- RMSNorm + cast to bf16 ----------
__global__ __launch_bounds__(256) void k_rmsnorm(const float* __restrict__ x,
                                                 const float* __restrict__ wn,
                                                 short* __restrict__ xn) {
  const int row = blockIdx.x;      // 8192 rows
  const int t = threadIdx.x;       // 256 threads, 4 floats each
  const float4 v = reinterpret_cast<const float4*>(x + (size_t)row * 1024)[t];
  float ss = v.x * v.x + v.y * v.y + v.z * v.z + v.w * v.w;
#pragma unroll
  for (int m = 32; m >= 1; m >>= 1) ss += __shfl_xor(ss, m, 64);
  __shared__ float red[4];
  if ((t & 63) == 0) red[t >> 6] = ss;
  __syncthreads();
  const float tot = red[0] + red[1] + red[2] + red[3];
  const float rr = rsqrtf(tot * (1.0f / 1024.0f) + 1e-5f);
  const float4 g = reinterpret_cast<const float4*>(wn)[t];
  bf16x4 o;
  o[0] = f2bf(v.x * rr * g.x);
  o[1] = f2bf(v.y * rr * g.y);
  o[2] = f2bf(v.z * rr * g.z);
  o[3] = f2bf(v.w * rr * g.w);
  reinterpret_cast<bf16x4*>(xn + (size_t)row * 1024)[t] = o;
}

// ---------- casts ----------
__global__ __launch_bounds__(256) void k_cast_bf(const float* __restrict__ in,
                                                 short* __restrict__ out, int n4) {
  int i = blockIdx.x * 256 + threadIdx.x;
  if (i >= n4) return;
  float4 v = reinterpret_cast<const float4*>(in)[i];
  bf16x4 o;
  o[0] = f2bf(v.x); o[1] = f2bf(v.y); o[2] = f2bf(v.z); o[3] = f2bf(v.w);
  reinterpret_cast<bf16x4*>(out)[i] = o;
}

__global__ __launch_bounds__(256) void k_cast_f16(const float* __restrict__ in,
                                                  _Float16* __restrict__ out, int n4) {
  int i = blockIdx.x * 256 + threadIdx.x;
  if (i >= n4) return;
  float4 v = reinterpret_cast<const float4*>(in)[i];
  _Float16 o[4] = {(_Float16)v.x, (_Float16)v.y, (_Float16)v.z, (_Float16)v.w};
  reinterpret_cast<ulong1*>(out)[i] = *reinterpret_cast<ulong1*>(o);
}

// ---------- QKV GEMM (bf16, m97 structure, 128x128xBK32, T1 XCD swizzle) ----------
__global__ __launch_bounds__(256) void k_gemm_qkv(const short* __restrict__ A,
                                                  const short* __restrict__ B,
                                                  const float* __restrict__ bias,
                                                  short* __restrict__ qb,
                                                  short* __restrict__ kb,
                                                  short* __restrict__ vb) {
  __shared__ __align__(16) short As[128 * 32];
  __shared__ __align__(16) short Bs[128 * 32];
  const int t = threadIdx.x;
  // T1: XCD-aware remap (nwg = 24*64 = 1536, 1536%8==0)
  const int orig = blockIdx.y * 24 + blockIdx.x;
  const int swz = (orig & 7) * 192 + (orig >> 3);
  const long bn0 = (long)(swz % 24) * 128;
  const long bm0 = (long)(swz / 24) * 128;
  const int w = t >> 6, l = t & 63;
  const int wr = (w >> 1) * 64, wc = (w & 1) * 64;
  const int lm = l & 15, h = l >> 4;
  f32x4 acc[4][4];
#pragma unroll
  for (int i = 0; i < 4; ++i)
#pragma unroll
    for (int j = 0; j < 4; ++j) acc[i][j] = (f32x4){0.f, 0.f, 0.f, 0.f};
  const int srow = t >> 2, scol = (t & 3) * 8;
  const short* Ag = A + (bm0 + srow) * 1024 + scol;
  const short* Bg = B + (bn0 + srow) * 1024 + scol;
  short* AsP = As + t * 8;
  short* BsP = Bs + t * 8;
  for (int kt = 0; kt < 32; ++kt) {
    const int k0 = kt << 5;
    gld_lds16(Ag + k0, AsP);
    gld_lds16(Ag + k0 + 64 * 1024, AsP + 2048);
    gld_lds16(Bg + k0, BsP);
    gld_lds16(Bg + k0 + 64 * 1024, BsP + 2048);
    __syncthreads();
    bf16x8 af[4], bfr[4];
#pragma unroll
    for (int mi = 0; mi < 4; ++mi)
      af[mi] = *reinterpret_cast<const bf16x8*>(As + (wr + mi * 16 + lm) * 32 + h * 8);
#pragma unroll
    for (int ni = 0; ni < 4; ++ni)
      bfr[ni] = *reinterpret_cast<const bf16x8*>(Bs + (wc + ni * 16 + lm) * 32 + h * 8);
    __builtin_amdgcn_s_setprio(1);
#pragma unroll
    for (int mi = 0; mi < 4; ++mi)
#pragma unroll
      for (int ni = 0; ni < 4; ++ni)
        acc[mi][ni] = __builtin_amdgcn_mfma_f32_16x16x32_bf16(af[mi], bfr[ni], acc[mi][ni], 0, 0, 0);
    __builtin_amdgcn_s_setprio(0);
    __syncthreads();
  }
#pragma unroll
  for (int ni = 0; ni < 4; ++ni) {
    const int ncol = (int)bn0 + wc + ni * 16 + lm;
    const float bv = bias[ncol];
    const int which = ncol >> 10;
    const int e = ncol & 1023;
#pragma unroll
    for (int mi = 0; mi < 4; ++mi) {
#pragma unroll
      for (int r = 0; r < 4; ++r) {
        const long mrow = bm0 + wr + mi * 16 + h * 4 + r;
        const float val = acc[mi][ni][r] + bv;
        const long off = (((mrow >> 11) * 16 + (e >> 6)) * 2048 + (mrow & 2047)) * 64 + (e & 63);
        if (which == 0) qb[off] = f2bf(val * 0.18033688011112042f);  // 0.125*log2(e)
        else if (which == 1) kb[off] = f2bf(val);
        else vb[off] = f2bf(val);
      }
    }
  }
}

// ---------- out-proj GEMM (fp16 inputs for precision, fp32 out) ----------
__global__ __launch_bounds__(256) void k_gemm_out(const _Float16* __restrict__ A,
                                                  const _Float16* __restrict__ B,
                                                  const float* __restrict__ bias,
                                                  float* __restrict__ outp) {
  __shared__ __align__(16) _Float16 As[128 * 32];
  __shared__ __align__(16) _Float16 Bs[128 * 32];
  const int t = threadIdx.x;
  // T1: nwg = 8*64 = 512, 512%8==0
  const int orig = blockIdx.y * 8 + blockIdx.x;
  const int swz = (orig & 7) * 64 + (orig >> 3);
  const long bn0 = (long)(swz % 8) * 128;
  const long bm0 = (long)(swz / 8) * 128;
  const int w = t >> 6, l = t & 63;
  const int wr = (w >> 1) * 64, wc = (w & 1) * 64;
  const int lm = l & 15, h = l >> 4;
  f32x4 acc[4][4];
#pragma unroll
  for (int i = 0; i < 4; ++i)
#pragma unroll
    for (int j = 0; j < 4; ++j) acc[i][j] = (f32x4){0.f, 0.f, 0.f, 0.f};
  const int srow = t >> 2, scol = (t & 3) * 8;
  const _Float16* Ag = A + (bm0 + srow) * 1024 + scol;
  const _Float16* Bg = B + (bn0 + srow) * 1024 + scol;
  _Float16* AsP = As + t * 8;
  _Float16* BsP = Bs + t * 8;
  for (int kt = 0; kt < 32; ++kt) {
    const int k0 = kt << 5;
    gld_lds16(Ag + k0, AsP);
    gld_lds16(Ag + k0 + 64 * 1024, AsP + 2048);
    gld_lds16(Bg + k0, BsP);
    gld_lds16(Bg + k0 + 64 * 1024, BsP + 2048);
    __syncthreads();
    f16x8 af[4], bfr[4];
#pragma unroll
    for (int mi = 0; mi < 4; ++mi)
      af[mi] = *reinterpret_cast<const f16x8*>(As + (wr + mi * 16 + lm) * 32 + h * 8);
#pragma unroll
    for (int ni = 0; ni < 4; ++ni)
      bfr[ni] = *reinterpret_cast<const f16x8*>(Bs + (wc + ni * 16 + lm) * 32 + h * 8);
    __builtin_amdgcn_s_setprio(1);
#pragma unroll
    for (int mi = 0; mi < 4; ++mi)
#pragma unroll
      for (int ni = 0; ni < 4; ++ni)
        acc[mi][ni] = __builtin_amdgcn_mfma_f32_16x16x32_f16(af[mi], bfr[ni], acc[mi][ni], 0, 0, 0);
    __builtin_amdgcn_s_setprio(0);
    __syncthreads();
  }
#pragma unroll
  for (int ni = 0; ni < 4; ++ni) {
    const int ncol = (int)bn0 + wc + ni * 16 + lm;
    const float bv = bias[ncol];
#pragma unroll
    for (int mi = 0; mi < 4; ++mi) {
#pragma unroll
      for (int r = 0; r < 4; ++r) {
        const long mrow = bm0 + wr + mi * 16 + h * 4 + r;
        outp[mrow * 1024 + ncol] = acc[mi][ni][r] + bv;
      }
    }
  }
}

// ---------- V transpose: v[BH][S][64] -> vT[BH][64][S] ----------
__global__ __launch_bounds__(256) void k_transpose_v(const short* __restrict__ v,
                                                     short* __restrict__ vt) {
  __shared__ short tile[64][72];
  const int bh = blockIdx.y, st = blockIdx.x;  // 32 s-tiles of 64
  const int t = threadIdx.x;
  const int r = t >> 2, c0 = (t & 3) * 16;
  const short* src = v + ((size_t)(bh * 2048 + st * 64 + r)) * 64 + c0;
  bf16x8 a = *reinterpret_cast<const bf16x8*>(src);
  bf16x8 b = *reinterpret_cast<const bf16x8*>(src + 8);
#pragma unroll
  for (int j = 0; j < 8; ++j) tile[r][c0 + j] = a[j];
#pragma unroll
  for (int j = 0; j < 8; ++j) tile[r][c0 + 8 + j] = b[j];
  __syncthreads();
  __align__(16) short tmp[16];
#pragma unroll
  for (int j = 0; j < 16; ++j) tmp[j] = tile[c0 + j][r];
  short* dst = vt + ((size_t)(bh * 64 + r)) * 2048 + st * 64 + c0;
  *reinterpret_cast<bf16x8*>(dst) = *reinterpret_cast<const bf16x8*>(tmp);
  *reinterpret_cast<bf16x8*>(dst + 8) = *reinterpret_cast<const bf16x8*>(tmp + 8);
}

// ---------- flash attention v5: 4-deep prefetch, counted vmcnt, raw barrier ----------
// v4 geometry (4 waves/block, 64 q-rows/wave, KBLK=32) + T3/T4: 4-buffer
// rotation, prologue stages tiles 0..2, loop top waits vmcnt(4) (tile t
// retired, t+1/t+2 in flight) + raw s_barrier (NO vmcnt(0) drain), then
// issues tile t+3. Safety: barrier(t+1) can't pass until all waves finished
// reading buf[t&3] (their reads complete before their pre-barrier MFMAs);
// tile t+4 (same buffer) is issued only after barrier(t+1). Tail prefetches
// clamp to tile 63 (junk reloads keep vmcnt accounting uniform; never read).
// + XCD swizzle: each XCD owns 8 whole heads (KV L2 footprint 8MB vs 64MB).
__global__ __launch_bounds__(256, 2) void k_attn(const short* __restrict__ q,
                                                 const short* __restrict__ k,
                                                 const short* __restrict__ vt,
                                                 _Float16* __restrict__ o) {
  __shared__ __align__(16) short Ks[4][2048];  // 32 keys x 64 d = 4KB x4
  __shared__ __align__(16) short Vs[4][2048];  // 64 d x 32 keys = 4KB x4
  // XCD swizzle: orig linear id -> work = (orig%8)*64 + orig/8  (512 = 8*64)
  const int orig = blockIdx.y * 8 + blockIdx.x;
  const int work = (orig & 7) * 64 + (orig >> 3);
  const int bh = work >> 3;    // 64 heads
  const int qt = work & 7;     // 8 q-tiles
  const int t = threadIdx.x;
  const int w = t >> 6, l = t & 63;
  const int lq = l & 31, hh = l >> 5;
  const int xr = lq & 7;
  const int qbase = qt * 256 + w * 64;

  // Q fragments: qf[qh][db] = Q[qbase+qh*32+lq][db*16 + hh*8 .. +8]
  bf16x8 qf[2][4];
#pragma unroll
  for (int qh = 0; qh < 2; ++qh) {
    const short* qp = q + ((size_t)(bh * 2048 + qbase + qh * 32 + lq)) * 64 + hh * 8;
#pragma unroll
    for (int db = 0; db < 4; ++db)
      qf[qh][db] = *reinterpret_cast<const bf16x8*>(qp + db * 16);
  }

  // staging: 256 granules (16B) per tensor per tile, 1 per thread
  const int gg = t;
  const int uK = gg ^ ((gg >> 3) & 7);            // K: row=gg>>3 (key), col=gg&7
  const int vrow = gg >> 2;                       // V: row=d (4 granules/row)
  const int vcol = (gg & 3) ^ (vrow & 3);
  const short* kh = k + (size_t)bh * 2048 * 64;
  const short* vh = vt + (size_t)bh * 64 * 2048;
  const short* ksrc = kh + uK * 8;                // + kt*2048 per iter
  const short* vsrc = vh + vrow * 2048 + vcol * 8;  // + kt*32 per iter

  // swizzled LDS read offsets (shorts)
  int koff[4], voff[2][2];
#pragma unroll
  for (int db = 0; db < 4; ++db)
    koff[db] = (lq * 8 + ((db * 2 + hh) ^ xr)) * 8;
#pragma unroll
  for (int dt = 0; dt < 2; ++dt)
#pragma unroll
    for (int kg = 0; kg < 2; ++kg)
      voff[dt][kg] = ((dt * 32 + lq) * 4 + ((kg * 2 + hh) ^ (lq & 3))) * 8;

  f32x16 oa00 = zero16(), oa01 = zero16();  // qh=0: dt=0,1
  f32x16 oa10 = zero16(), oa11 = zero16();  // qh=1: dt=0,1
  float mr0 = -1e30f, mr1 = -1e30f, lr0 = 0.f, lr1 = 0.f;

  // prologue: stage tiles 0..2 (6 loads in flight)
#pragma unroll
  for (int p = 0; p < 3; ++p) {
    gld_lds16(ksrc + p * 2048, &Ks[p][gg * 8]);
    gld_lds16(vsrc + p * 32, &Vs[p][gg * 8]);
  }

  for (int kt = 0; kt < 64; ++kt) {
    // tile kt retired (2 oldest); kt+1, kt+2 stay in flight across the barrier
    asm volatile("s_waitcnt vmcnt(4)" ::: "memory");
    __builtin_amdgcn_s_barrier();
    // stage tile kt+3 into buf[(kt+3)&3] (that buffer's readers finished at
    // barrier(kt); clamp keeps tail vmcnt accounting uniform)
    int kn = kt + 3; if (kn > 63) kn = 63;
    gld_lds16(ksrc + kn * 2048, &Ks[(kt + 3) & 3][gg * 8]);
    gld_lds16(vsrc + kn * 32, &Vs[(kt + 3) & 3][gg * 8]);

    const short* kb_ = Ks[kt & 3];
    const short* vb_ = Vs[kt & 3];
    f32x16 s0 = zero16(), s1 = zero16();  // qh=0, qh=1 (32 keys x 32 q each)
    __builtin_amdgcn_s_setprio(1);
#pragma unroll
    for (int db = 0; db < 4; ++db) {
      bf16x8 kf = *reinterpret_cast<const bf16x8*>(kb_ + koff[db]);
      s0 = __builtin_amdgcn_mfma_f32_32x32x16_bf16(kf, qf[0][db], s0, 0, 0, 0);
      s1 = __builtin_amdgcn_mfma_f32_32x32x16_bf16(kf, qf[1][db], s1, 0, 0, 0);
    }
    __builtin_amdgcn_s_setprio(0);
    // per-q-row tile max
    float tm0 = xhalf_max(tmax16(s0));
    float tm1 = xhalf_max(tmax16(s1));
    // defer-max rescale (log2 domain, THR=8 => P <= 256)
    if (!__all((tm0 <= mr0 + 8.f) && (tm1 <= mr1 + 8.f))) {
      const float mn0 = fmaxf(mr0, tm0), mn1 = fmaxf(mr1, tm1);
      const float c0 = EXP2(mr0 - mn0), c1 = EXP2(mr1 - mn1);
      lr0 *= c0; lr1 *= c1;
#pragma unroll
      for (int r = 0; r < 16; ++r) {
        oa00[r] *= c0; oa01[r] *= c0;
        oa10[r] *= c1; oa11[r] *= c1;
      }
      mr0 = mn0; mr1 = mn1;
    }
#pragma unroll
    for (int r = 0; r < 16; ++r) {
      s0[r] = EXP2(s0[r] - mr0);
      s1[r] = EXP2(s1[r] - mr1);
    }
    lr0 += tsum16(s0);  // per-half partial; combined once at the end
    lr1 += tsum16(s1);
    // PV: per 16-key group build P-frags for both qh; V-frags reused across qh
    __builtin_amdgcn_s_setprio(1);
#pragma unroll
    for (int kg = 0; kg < 2; ++kg) {
      const int b0 = kg * 8;
      unsigned p00 = cvtpk_bf16(s0[b0 + 0], s0[b0 + 1]);
      unsigned p01 = cvtpk_bf16(s0[b0 + 2], s0[b0 + 3]);
      unsigned p02 = cvtpk_bf16(s0[b0 + 4], s0[b0 + 5]);
      unsigned p03 = cvtpk_bf16(s0[b0 + 6], s0[b0 + 7]);
      plane32_swap(p00, p02);
      plane32_swap(p01, p03);
      u32x4 pw0 = {p00, p01, p02, p03};
      bf16x8 pf0 = *reinterpret_cast<bf16x8*>(&pw0);
      unsigned p10 = cvtpk_bf16(s1[b0 + 0], s1[b0 + 1]);
      unsigned p11 = cvtpk_bf16(s1[b0 + 2], s1[b0 + 3]);
      unsigned p12 = cvtpk_bf16(s1[b0 + 4], s1[b0 + 5]);
      unsigned p13 = cvtpk_bf16(s1[b0 + 6], s1[b0 + 7]);
      plane32_swap(p10, p12);
      plane32_swap(p11, p13);
      u32x4 pw1 = {p10, p11, p12, p13};
      bf16x8 pf1 = *reinterpret_cast<bf16x8*>(&pw1);
      bf16x8 vf0 = *reinterpret_cast<const bf16x8*>(vb_ + voff[0][kg]);
      oa00 = __builtin_amdgcn_mfma_f32_32x32x16_bf16(vf0, pf0, oa00, 0, 0, 0);
      oa10 = __builtin_amdgcn_mfma_f32_32x32x16_bf16(vf0, pf1, oa10, 0, 0, 0);
      bf16x8 vf1 = *reinterpret_cast<const bf16x8*>(vb_ + voff[1][kg]);
      oa01 = __builtin_amdgcn_mfma_f32_32x32x16_bf16(vf1, pf0, oa01, 0, 0, 0);
      oa11 = __builtin_amdgcn_mfma_f32_32x32x16_bf16(vf1, pf1, oa11, 0, 0, 0);
    }
    __builtin_amdgcn_s_setprio(0);
  }
  const float inv0 = 1.0f / xhalf_sum(lr0);
  const float inv1 = 1.0f / xhalf_sum(lr1);
  const int b = bh >> 4, hd = bh & 15;
  _Float16* ob0 = o + ((size_t)(b * 2048 + qbase + lq)) * 1024 + hd * 64;
  _Float16* ob1 = ob0 + 32 * 1024;
#pragma unroll
  for (int r2 = 0; r2 < 16; ++r2) {
    const int d0 = (r2 & 3) + 8 * (r2 >> 2) + 4 * hh;  // 32x32 C layout
    ob0[d0] = (_Float16)(oa00[r2] * inv0);
    ob0[d0 + 32] = (_Float16)(oa01[r2] * inv0);
    ob1[d0] = (_Float16)(oa10[r2] * inv1);
    ob1[d0 + 32] = (_Float16)(oa11[r2] * inv1);
  }
}

// ---------- launch ----------
extern "C" void kernel_launch(void* const* d_in, const int* in_sizes, int n_in,
                              void* d_out, int out_size, void* d_ws, size_t ws_size,
                              hipStream_t stream) {
  const float* x = (const float*)d_in[0];
  const float* w_in = (const float*)d_in[1];
  const float* b_in = (const float*)d_in[2];
  const float* w_norm = (const float*)d_in[3];
  const float* w_out = (const float*)d_in[4];
  const float* b_out = (const float*)d_in[5];
  float* out = (float*)d_out;
  char* ws = (char*)d_ws;
  short* xn = (short*)(ws);                       // 16 MB [8192][1024] bf16
  short* win_b = (short*)(ws + 16777216);         // 6 MB  [3072][1024] bf16
  _Float16* wout_h = (_Float16*)(ws + 23068672);  // 2 MB  [1024][1024] f16
  short* qb = (short*)(ws + 25165824);            // 16 MB [64][2048][64] bf16
  short* kb = (short*)(ws + 41943040);            // 16 MB
  short* vb = (short*)(ws + 58720256);            // 16 MB
  short* vt = (short*)(ws + 75497472);            // 16 MB [64][64][2048]
  _Float16* ob = (_Float16*)vb;                   // alias: v dead after transpose

  k_cast_bf<<<3072, 256, 0, stream>>>(w_in, win_b, 786432);
  k_cast_f16<<<1024, 256, 0, stream>>>(w_out, wout_h, 262144);
  k_rmsnorm<<<8192, 256, 0, stream>>>(x, w_norm, xn);
  k_gemm_qkv<<<dim3(24, 64), 256, 0, stream>>>(xn, win_b, b_in, qb, kb, vb);
  k_transpose_v<<<dim3(32, 64), 256, 0, stream>>>(vb, vt);
  k_attn<<<dim3(8, 64), 256, 0, stream>>>(qb, kb, vt, ob);
  k_gemm_out<<<dim3(8, 64), 256, 0, stream>>>(ob, wout_h, b_out, out);
}

// Round 8
// 226.583 us; speedup vs baseline: 1.0677x; 1.0034x over previous
//
#include <hip/hip_runtime.h>
#include <stdint.h>

typedef short bf16x4 __attribute__((ext_vector_type(4)));
typedef short bf16x8 __attribute__((ext_vector_type(8)));
typedef _Float16 f16x8 __attribute__((ext_vector_type(8)));
typedef float f32x4 __attribute__((ext_vector_type(4)));
typedef float f32x16 __attribute__((ext_vector_type(16)));
typedef unsigned int u32x4 __attribute__((ext_vector_type(4)));
typedef unsigned int u32x2 __attribute__((ext_vector_type(2)));

#if __has_builtin(__builtin_amdgcn_exp2f)
#define EXP2 __builtin_amdgcn_exp2f
#else
#define EXP2 exp2f
#endif

// ---------- helpers ----------
__device__ __forceinline__ short f2bf(float f) {  // RNE f32->bf16 (finite inputs)
  union { float f; uint32_t u; } v; v.f = f;
  uint32_t r = (v.u + 0x7fffu + ((v.u >> 16) & 1u)) >> 16;
  return (short)(uint16_t)r;
}

__device__ __forceinline__ unsigned cvtpk_bf16(float lo, float hi) {
  unsigned r;
  asm("v_cvt_pk_bf16_f32 %0, %1, %2" : "=v"(r) : "v"(lo), "v"(hi));
  return r;
}

// v_permlane32_swap_b32 via the BUILTIN (hazard-safe; round-5 verified).
#if __has_builtin(__builtin_amdgcn_permlane32_swap)
__device__ __forceinline__ void plane32_swap(unsigned& a, unsigned& b) {
  u32x2 r = __builtin_amdgcn_permlane32_swap(a, b, false, false);
  a = r[0]; b = r[1];
}
__device__ __forceinline__ float xhalf_max(float x) {
  unsigned xu = __builtin_bit_cast(unsigned, x);
  u32x2 r = __builtin_amdgcn_permlane32_swap(xu, xu, false, false);
  return fmaxf(__builtin_bit_cast(float, r[0]), __builtin_bit_cast(float, r[1]));
}
__device__ __forceinline__ float xhalf_sum(float x) {
  unsigned xu = __builtin_bit_cast(unsigned, x);
  u32x2 r = __builtin_amdgcn_permlane32_swap(xu, xu, false, false);
  return __builtin_bit_cast(float, r[0]) + __builtin_bit_cast(float, r[1]);
}
#else
__device__ __forceinline__ void plane32_swap(unsigned& a, unsigned& b) {
  asm("s_nop 1\n\tv_permlane32_swap_b32 %0, %1" : "+v"(a), "+v"(b));
}
__device__ __forceinline__ float xhalf_max(float x) { return fmaxf(x, __shfl_xor(x, 32, 64)); }
__device__ __forceinline__ float xhalf_sum(float x) { return x + __shfl_xor(x, 32, 64); }
#endif

__device__ __forceinline__ float fmax3(float a, float b, float c) {
  return fmaxf(fmaxf(a, b), c);  // clang fuses to v_max3_f32
}

__device__ __forceinline__ float tmax16(const f32x16& s) {
  float a0 = fmax3(s[0], s[1], s[2]);
  float a1 = fmax3(s[3], s[4], s[5]);
  float a2 = fmax3(s[6], s[7], s[8]);
  float a3 = fmax3(s[9], s[10], s[11]);
  float a4 = fmax3(s[12], s[13], s[14]);
  float b0 = fmax3(a0, a1, s[15]);
  float b1 = fmax3(a2, a3, a4);
  return fmaxf(b0, b1);
}
__device__ __forceinline__ float tsum16(const f32x16& s) {
  float a0 = (s[0] + s[1]) + (s[2] + s[3]);
  float a1 = (s[4] + s[5]) + (s[6] + s[7]);
  float a2 = (s[8] + s[9]) + (s[10] + s[11]);
  float a3 = (s[12] + s[13]) + (s[14] + s[15]);
  return (a0 + a1) + (a2 + a3);
}

__device__ __forceinline__ f32x16 zero16() {
  f32x16 z;
#pragma unroll
  for (int i = 0; i < 16; ++i) z[i] = 0.f;
  return z;
}

__device__ __forceinline__ void gld_lds16(const void* g, void* l) {
  __builtin_amdgcn_global_load_lds(
      (__attribute__((address_space(1))) const void*)g,
      (__attribute__((address_space(3))) void*)l, 16, 0, 0);
}

// ---------- RMSNorm + cast to bf16 ----------
__global__ __launch_bounds__(256) void k_rmsnorm(const float* __restrict__ x,
                                                 const float* __restrict__ wn,
                                                 short* __restrict__ xn) {
  const int row = blockIdx.x;      // 8192 rows
  const int t = threadIdx.x;       // 256 threads, 4 floats each
  const float4 v = reinterpret_cast<const float4*>(x + (size_t)row * 1024)[t];
  float ss = v.x * v.x + v.y * v.y + v.z * v.z + v.w * v.w;
#pragma unroll
  for (int m = 32; m >= 1; m >>= 1) ss += __shfl_xor(ss, m, 64);
  __shared__ float red[4];
  if ((t & 63) == 0) red[t >> 6] = ss;
  __syncthreads();
  const float tot = red[0] + red[1] + red[2] + red[3];
  const float rr = rsqrtf(tot * (1.0f / 1024.0f) + 1e-5f);
  const float4 g = reinterpret_cast<const float4*>(wn)[t];
  bf16x4 o;
  o[0] = f2bf(v.x * rr * g.x);
  o[1] = f2bf(v.y * rr * g.y);
  o[2] = f2bf(v.z * rr * g.z);
  o[3] = f2bf(v.w * rr * g.w);
  reinterpret_cast<bf16x4*>(xn + (size_t)row * 1024)[t] = o;
}

// ---------- casts ----------
__global__ __launch_bounds__(256) void k_cast_bf(const float* __restrict__ in,
                                                 short* __restrict__ out, int n4) {
  int i = blockIdx.x * 256 + threadIdx.x;
  if (i >= n4) return;
  float4 v = reinterpret_cast<const float4*>(in)[i];
  bf16x4 o;
  o[0] = f2bf(v.x); o[1] = f2bf(v.y); o[2] = f2bf(v.z); o[3] = f2bf(v.w);
  reinterpret_cast<bf16x4*>(out)[i] = o;
}

__global__ __launch_bounds__(256) void k_cast_f16(const float* __restrict__ in,
                                                  _Float16* __restrict__ out, int n4) {
  int i = blockIdx.x * 256 + threadIdx.x;
  if (i >= n4) return;
  float4 v = reinterpret_cast<const float4*>(in)[i];
  _Float16 o[4] = {(_Float16)v.x, (_Float16)v.y, (_Float16)v.z, (_Float16)v.w};
  reinterpret_cast<ulong1*>(out)[i] = *reinterpret_cast<ulong1*>(o);
}

// ---------- QKV GEMM (bf16, m97 structure, 128x128xBK32, T1 XCD swizzle) ----------
__global__ __launch_bounds__(256) void k_gemm_qkv(const short* __restrict__ A,
                                                  const short* __restrict__ B,
                                                  const float* __restrict__ bias,
                                                  short* __restrict__ qb,
                                                  short* __restrict__ kb,
                                                  short* __restrict__ vb) {
  __shared__ __align__(16) short As[128 * 32];
  __shared__ __align__(16) short Bs[128 * 32];
  const int t = threadIdx.x;
  // T1: XCD-aware remap (nwg = 24*64 = 1536, 1536%8==0)
  const int orig = blockIdx.y * 24 + blockIdx.x;
  const int swz = (orig & 7) * 192 + (orig >> 3);
  const long bn0 = (long)(swz % 24) * 128;
  const long bm0 = (long)(swz / 24) * 128;
  const int w = t >> 6, l = t & 63;
  const int wr = (w >> 1) * 64, wc = (w & 1) * 64;
  const int lm = l & 15, h = l >> 4;
  f32x4 acc[4][4];
#pragma unroll
  for (int i = 0; i < 4; ++i)
#pragma unroll
    for (int j = 0; j < 4; ++j) acc[i][j] = (f32x4){0.f, 0.f, 0.f, 0.f};
  const int srow = t >> 2, scol = (t & 3) * 8;
  const short* Ag = A + (bm0 + srow) * 1024 + scol;
  const short* Bg = B + (bn0 + srow) * 1024 + scol;
  short* AsP = As + t * 8;
  short* BsP = Bs + t * 8;
  for (int kt = 0; kt < 32; ++kt) {
    const int k0 = kt << 5;
    gld_lds16(Ag + k0, AsP);
    gld_lds16(Ag + k0 + 64 * 1024, AsP + 2048);
    gld_lds16(Bg + k0, BsP);
    gld_lds16(Bg + k0 + 64 * 1024, BsP + 2048);
    __syncthreads();
    bf16x8 af[4], bfr[4];
#pragma unroll
    for (int mi = 0; mi < 4; ++mi)
      af[mi] = *reinterpret_cast<const bf16x8*>(As + (wr + mi * 16 + lm) * 32 + h * 8);
#pragma unroll
    for (int ni = 0; ni < 4; ++ni)
      bfr[ni] = *reinterpret_cast<const bf16x8*>(Bs + (wc + ni * 16 + lm) * 32 + h * 8);
    __builtin_amdgcn_s_setprio(1);
#pragma unroll
    for (int mi = 0; mi < 4; ++mi)
#pragma unroll
      for (int ni = 0; ni < 4; ++ni)
        acc[mi][ni] = __builtin_amdgcn_mfma_f32_16x16x32_bf16(af[mi], bfr[ni], acc[mi][ni], 0, 0, 0);
    __builtin_amdgcn_s_setprio(0);
    __syncthreads();
  }
#pragma unroll
  for (int ni = 0; ni < 4; ++ni) {
    const int ncol = (int)bn0 + wc + ni * 16 + lm;
    const float bv = bias[ncol];
    const int which = ncol >> 10;
    const int e = ncol & 1023;
#pragma unroll
    for (int mi = 0; mi < 4; ++mi) {
#pragma unroll
      for (int r = 0; r < 4; ++r) {
        const long mrow = bm0 + wr + mi * 16 + h * 4 + r;
        const float val = acc[mi][ni][r] + bv;
        const long off = (((mrow >> 11) * 16 + (e >> 6)) * 2048 + (mrow & 2047)) * 64 + (e & 63);
        if (which == 0) qb[off] = f2bf(val * 0.18033688011112042f);  // 0.125*log2(e)
        else if (which == 1) kb[off] = f2bf(val);
        else vb[off] = f2bf(val);
      }
    }
  }
}

// ---------- out-proj GEMM (fp16 inputs for precision, fp32 out) ----------
__global__ __launch_bounds__(256) void k_gemm_out(const _Float16* __restrict__ A,
                                                  const _Float16* __restrict__ B,
                                                  const float* __restrict__ bias,
                                                  float* __restrict__ outp) {
  __shared__ __align__(16) _Float16 As[128 * 32];
  __shared__ __align__(16) _Float16 Bs[128 * 32];
  const int t = threadIdx.x;
  // T1: nwg = 8*64 = 512, 512%8==0
  const int orig = blockIdx.y * 8 + blockIdx.x;
  const int swz = (orig & 7) * 64 + (orig >> 3);
  const long bn0 = (long)(swz % 8) * 128;
  const long bm0 = (long)(swz / 8) * 128;
  const int w = t >> 6, l = t & 63;
  const int wr = (w >> 1) * 64, wc = (w & 1) * 64;
  const int lm = l & 15, h = l >> 4;
  f32x4 acc[4][4];
#pragma unroll
  for (int i = 0; i < 4; ++i)
#pragma unroll
    for (int j = 0; j < 4; ++j) acc[i][j] = (f32x4){0.f, 0.f, 0.f, 0.f};
  const int srow = t >> 2, scol = (t & 3) * 8;
  const _Float16* Ag = A + (bm0 + srow) * 1024 + scol;
  const _Float16* Bg = B + (bn0 + srow) * 1024 + scol;
  _Float16* AsP = As + t * 8;
  _Float16* BsP = Bs + t * 8;
  for (int kt = 0; kt < 32; ++kt) {
    const int k0 = kt << 5;
    gld_lds16(Ag + k0, AsP);
    gld_lds16(Ag + k0 + 64 * 1024, AsP + 2048);
    gld_lds16(Bg + k0, BsP);
    gld_lds16(Bg + k0 + 64 * 1024, BsP + 2048);
    __syncthreads();
    f16x8 af[4], bfr[4];
#pragma unroll
    for (int mi = 0; mi < 4; ++mi)
      af[mi] = *reinterpret_cast<const f16x8*>(As + (wr + mi * 16 + lm) * 32 + h * 8);
#pragma unroll
    for (int ni = 0; ni < 4; ++ni)
      bfr[ni] = *reinterpret_cast<const f16x8*>(Bs + (wc + ni * 16 + lm) * 32 + h * 8);
    __builtin_amdgcn_s_setprio(1);
#pragma unroll
    for (int mi = 0; mi < 4; ++mi)
#pragma unroll
      for (int ni = 0; ni < 4; ++ni)
        acc[mi][ni] = __builtin_amdgcn_mfma_f32_16x16x32_f16(af[mi], bfr[ni], acc[mi][ni], 0, 0, 0);
    __builtin_amdgcn_s_setprio(0);
    __syncthreads();
  }
#pragma unroll
  for (int ni = 0; ni < 4; ++ni) {
    const int ncol = (int)bn0 + wc + ni * 16 + lm;
    const float bv = bias[ncol];
#pragma unroll
    for (int mi = 0; mi < 4; ++mi) {
#pragma unroll
      for (int r = 0; r < 4; ++r) {
        const long mrow = bm0 + wr + mi * 16 + h * 4 + r;
        outp[mrow * 1024 + ncol] = acc[mi][ni][r] + bv;
      }
    }
  }
}

// ---------- V transpose: v[BH][S][64] -> vT[BH][64][S] ----------
__global__ __launch_bounds__(256) void k_transpose_v(const short* __restrict__ v,
                                                     short* __restrict__ vt) {
  __shared__ short tile[64][72];
  const int bh = blockIdx.y, st = blockIdx.x;  // 32 s-tiles of 64
  const int t = threadIdx.x;
  const int r = t >> 2, c0 = (t & 3) * 16;
  const short* src = v + ((size_t)(bh * 2048 + st * 64 + r)) * 64 + c0;
  bf16x8 a = *reinterpret_cast<const bf16x8*>(src);
  bf16x8 b = *reinterpret_cast<const bf16x8*>(src + 8);
#pragma unroll
  for (int j = 0; j < 8; ++j) tile[r][c0 + j] = a[j];
#pragma unroll
  for (int j = 0; j < 8; ++j) tile[r][c0 + 8 + j] = b[j];
  __syncthreads();
  __align__(16) short tmp[16];
#pragma unroll
  for (int j = 0; j < 16; ++j) tmp[j] = tile[c0 + j][r];
  short* dst = vt + ((size_t)(bh * 64 + r)) * 2048 + st * 64 + c0;
  *reinterpret_cast<bf16x8*>(dst) = *reinterpret_cast<const bf16x8*>(tmp);
  *reinterpret_cast<bf16x8*>(dst + 8) = *reinterpret_cast<const bf16x8*>(tmp + 8);
}

// ---------- flash attention v6: BARRIER-FREE wave-private pipelines ----------
// Each of the 4 waves owns a private 16KB LDS region (2-deep x (4KB K + 4KB
// V)) and free-runs its own 64-iteration loop with counted per-wave vmcnt:
//   top: s_waitcnt vmcnt(8)  (tile t's 8 loads done; t+1's 8 in flight)
//   read 8 frags from buf[t&1]; s_waitcnt lgkmcnt(0) (reads drained)
//   issue 8 gld_lds for tile t+2 into buf[t&1]   (overwrite now safe)
//   compute QK -> softmax -> PV
// ZERO s_barrier in the kernel: no cross-wave hazards (buffers private), so
// the CU scheduler always has waves in different phases -> MFMA/VALU/trans/DS
// overlap across waves instead of lockstep-serializing (the round-7 stall).
// Tail prefetches clamp to tile 63 to keep vmcnt accounting uniform.
__global__ __launch_bounds__(256, 2) void k_attn(const short* __restrict__ q,
                                                 const short* __restrict__ k,
                                                 const short* __restrict__ vt,
                                                 _Float16* __restrict__ o) {
  __shared__ __align__(16) short lds[4][8192];  // 16KB per wave, 64KB total
  // XCD swizzle: each XCD owns 8 whole heads (KV L2 footprint 8MB vs 64MB)
  const int orig = blockIdx.y * 8 + blockIdx.x;
  const int work = (orig & 7) * 64 + (orig >> 3);
  const int bh = work >> 3;    // 64 heads
  const int qt = work & 7;     // 8 q-tiles
  const int t = threadIdx.x;
  const int w = t >> 6, l = t & 63;
  const int lq = l & 31, hh = l >> 5;
  const int xr = lq & 7;
  const int qbase = qt * 256 + w * 64;
  short* Kb = &lds[w][0];      // [2][2048]
  short* Vb = &lds[w][4096];   // [2][2048]

  // Q fragments: qf[qh][db] = Q[qbase+qh*32+lq][db*16 + hh*8 .. +8]
  bf16x8 qf[2][4];
#pragma unroll
  for (int qh = 0; qh < 2; ++qh) {
    const short* qp = q + ((size_t)(bh * 2048 + qbase + qh * 32 + lq)) * 64 + hh * 8;
#pragma unroll
    for (int db = 0; db < 4; ++db)
      qf[qh][db] = *reinterpret_cast<const bf16x8*>(qp + db * 16);
  }

  // per-wave staging: 256 granules (16B) per tensor per tile, 4 instr each
  const short* kh = k + (size_t)bh * 2048 * 64;
  const short* vh = vt + (size_t)bh * 64 * 2048;
  const short* ks4[4];
  const short* vs4[4];
#pragma unroll
  for (int i = 0; i < 4; ++i) {
    const int g = i * 64 + l;
    const int uK = g ^ ((g >> 3) & 7);          // K: row=g>>3 (key), col swizzled
    ks4[i] = kh + uK * 8;                       // + kt*2048 per tile
    const int vr = g >> 2;                      // V: row=d, 4 granules/row
    const int vc = (g & 3) ^ (vr & 3);
    vs4[i] = vh + vr * 2048 + vc * 8;           // + kt*32 per tile
  }

  // swizzled LDS read offsets (shorts, within one 2048-short tile)
  int koff[4], voff[2][2];
#pragma unroll
  for (int db = 0; db < 4; ++db)
    koff[db] = (lq * 8 + ((db * 2 + hh) ^ xr)) * 8;
#pragma unroll
  for (int dt = 0; dt < 2; ++dt)
#pragma unroll
    for (int kg = 0; kg < 2; ++kg)
      voff[dt][kg] = ((dt * 32 + lq) * 4 + ((kg * 2 + hh) ^ (lq & 3))) * 8;

  f32x16 oa00 = zero16(), oa01 = zero16();  // qh=0: dt=0,1
  f32x16 oa10 = zero16(), oa11 = zero16();  // qh=1: dt=0,1
  float mr0 = -1e30f, mr1 = -1e30f, lr0 = 0.f, lr1 = 0.f;

  // prologue: stage tiles 0 (buf0) and 1 (buf1): 16 loads in flight
#pragma unroll
  for (int p = 0; p < 2; ++p) {
#pragma unroll
    for (int i = 0; i < 4; ++i)
      gld_lds16(ks4[i] + p * 2048, Kb + p * 2048 + i * 512 + l * 8);
#pragma unroll
    for (int i = 0; i < 4; ++i)
      gld_lds16(vs4[i] + p * 32, Vb + p * 2048 + i * 512 + l * 8);
  }

#pragma unroll 2
  for (int kt = 0; kt < 64; ++kt) {
    // tile kt's 8 loads retired; kt+1's 8 stay in flight (per-wave vmcnt)
    asm volatile("s_waitcnt vmcnt(8)" ::: "memory");
    const int buf = kt & 1;
    const short* kb_ = Kb + buf * 2048;
    const short* vb_ = Vb + buf * 2048;
    bf16x8 kf[4], vfr[2][2];
#pragma unroll
    for (int db = 0; db < 4; ++db)
      kf[db] = *reinterpret_cast<const bf16x8*>(kb_ + koff[db]);
#pragma unroll
    for (int dt = 0; dt < 2; ++dt)
#pragma unroll
      for (int kg = 0; kg < 2; ++kg)
        vfr[dt][kg] = *reinterpret_cast<const bf16x8*>(vb_ + voff[dt][kg]);
    asm volatile("s_waitcnt lgkmcnt(0)" ::: "memory");  // frags in regs
    __builtin_amdgcn_sched_barrier(0);                  // rule #18 fence
    // stage tile kt+2 into buf[kt&1] (its reads just drained; clamp = junk
    // reload of tile 63, never read, keeps vmcnt accounting uniform)
    int kn = kt + 2; if (kn > 63) kn = 63;
#pragma unroll
    for (int i = 0; i < 4; ++i)
      gld_lds16(ks4[i] + kn * 2048, (short*)kb_ + i * 512 + l * 8);
#pragma unroll
    for (int i = 0; i < 4; ++i)
      gld_lds16(vs4[i] + kn * 32, (short*)vb_ + i * 512 + l * 8);

    f32x16 s0 = zero16(), s1 = zero16();  // qh=0, qh=1 (32 keys x 32 q each)
    __builtin_amdgcn_s_setprio(1);
#pragma unroll
    for (int db = 0; db < 4; ++db) {
      s0 = __builtin_amdgcn_mfma_f32_32x32x16_bf16(kf[db], qf[0][db], s0, 0, 0, 0);
      s1 = __builtin_amdgcn_mfma_f32_32x32x16_bf16(kf[db], qf[1][db], s1, 0, 0, 0);
    }
    __builtin_amdgcn_s_setprio(0);
    // per-q-row tile max
    float tm0 = xhalf_max(tmax16(s0));
    float tm1 = xhalf_max(tmax16(s1));
    // defer-max rescale (log2 domain, THR=8 => P <= 256)
    if (!__all((tm0 <= mr0 + 8.f) && (tm1 <= mr1 + 8.f))) {
      const float mn0 = fmaxf(mr0, tm0), mn1 = fmaxf(mr1, tm1);
      const float c0 = EXP2(mr0 - mn0), c1 = EXP2(mr1 - mn1);
      lr0 *= c0; lr1 *= c1;
#pragma unroll
      for (int r = 0; r < 16; ++r) {
        oa00[r] *= c0; oa01[r] *= c0;
        oa10[r] *= c1; oa11[r] *= c1;
      }
      mr0 = mn0; mr1 = mn1;
    }
#pragma unroll
    for (int r = 0; r < 16; ++r) {
      s0[r] = EXP2(s0[r] - mr0);
      s1[r] = EXP2(s1[r] - mr1);
    }
    lr0 += tsum16(s0);  // per-half partial; combined once at the end
    lr1 += tsum16(s1);
    // PV: per 16-key group build P-frags for both qh; V-frags reused across qh
    __builtin_amdgcn_s_setprio(1);
#pragma unroll
    for (int kg = 0; kg < 2; ++kg) {
      const int b0 = kg * 8;
      unsigned p00 = cvtpk_bf16(s0[b0 + 0], s0[b0 + 1]);
      unsigned p01 = cvtpk_bf16(s0[b0 + 2], s0[b0 + 3]);
      unsigned p02 = cvtpk_bf16(s0[b0 + 4], s0[b0 + 5]);
      unsigned p03 = cvtpk_bf16(s0[b0 + 6], s0[b0 + 7]);
      plane32_swap(p00, p02);
      plane32_swap(p01, p03);
      u32x4 pw0 = {p00, p01, p02, p03};
      bf16x8 pf0 = *reinterpret_cast<bf16x8*>(&pw0);
      unsigned p10 = cvtpk_bf16(s1[b0 + 0], s1[b0 + 1]);
      unsigned p11 = cvtpk_bf16(s1[b0 + 2], s1[b0 + 3]);
      unsigned p12 = cvtpk_bf16(s1[b0 + 4], s1[b0 + 5]);
      unsigned p13 = cvtpk_bf16(s1[b0 + 6], s1[b0 + 7]);
      plane32_swap(p10, p12);
      plane32_swap(p11, p13);
      u32x4 pw1 = {p10, p11, p12, p13};
      bf16x8 pf1 = *reinterpret_cast<bf16x8*>(&pw1);
      oa00 = __builtin_amdgcn_mfma_f32_32x32x16_bf16(vfr[0][kg], pf0, oa00, 0, 0, 0);
      oa10 = __builtin_amdgcn_mfma_f32_32x32x16_bf16(vfr[0][kg], pf1, oa10, 0, 0, 0);
      oa01 = __builtin_amdgcn_mfma_f32_32x32x16_bf16(vfr[1][kg], pf0, oa01, 0, 0, 0);
      oa11 = __builtin_amdgcn_mfma_f32_32x32x16_bf16(vfr[1][kg], pf1, oa11, 0, 0, 0);
    }
    __builtin_amdgcn_s_setprio(0);
  }
  const float inv0 = 1.0f / xhalf_sum(lr0);
  const float inv1 = 1.0f / xhalf_sum(lr1);
  const int b = bh >> 4, hd = bh & 15;
  _Float16* ob0 = o + ((size_t)(b * 2048 + qbase + lq)) * 1024 + hd * 64;
  _Float16* ob1 = ob0 + 32 * 1024;
#pragma unroll
  for (int r2 = 0; r2 < 16; ++r2) {
    const int d0 = (r2 & 3) + 8 * (r2 >> 2) + 4 * hh;  // 32x32 C layout
    ob0[d0] = (_Float16)(oa00[r2] * inv0);
    ob0[d0 + 32] = (_Float16)(oa01[r2] * inv0);
    ob1[d0] = (_Float16)(oa10[r2] * inv1);
    ob1[d0 + 32] = (_Float16)(oa11[r2] * inv1);
  }
}

// ---------- launch ----------
extern "C" void kernel_launch(void* const* d_in, const int* in_sizes, int n_in,
                              void* d_out, int out_size, void* d_ws, size_t ws_size,
                              hipStream_t stream) {
  const float* x = (const float*)d_in[0];
  const float* w_in = (const float*)d_in[1];
  const float* b_in = (const float*)d_in[2];
  const float* w_norm = (const float*)d_in[3];
  const float* w_out = (const float*)d_in[4];
  const float* b_out = (const float*)d_in[5];
  float* out = (float*)d_out;
  char* ws = (char*)d_ws;
  short* xn = (short*)(ws);                       // 16 MB [8192][1024] bf16
  short* win_b = (short*)(ws + 16777216);         // 6 MB  [3072][1024] bf16
  _Float16* wout_h = (_Float16*)(ws + 23068672);  // 2 MB  [1024][1024] f16
  short* qb = (short*)(ws + 25165824);            // 16 MB [64][2048][64] bf16
  short* kb = (short*)(ws + 41943040);            // 16 MB
  short* vb = (short*)(ws + 58720256);            // 16 MB
  short* vt = (short*)(ws + 75497472);            // 16 MB [64][64][2048]
  _Float16* ob = (_Float16*)vb;                   // alias: v dead after transpose

  k_cast_bf<<<3072, 256, 0, stream>>>(w_in, win_b, 786432);
  k_cast_f16<<<1024, 256, 0, stream>>>(w_out, wout_h, 262144);
  k_rmsnorm<<<8192, 256, 0, stream>>>(x, w_norm, xn);
  k_gemm_qkv<<<dim3(24, 64), 256, 0, stream>>>(xn, win_b, b_in, qb, kb, vb);
  k_transpose_v<<<dim3(32, 64), 256, 0, stream>>>(vb, vt);
  k_attn<<<dim3(8, 64), 256, 0, stream>>>(qb, kb, vt, ob);
  k_gemm_out<<<dim3(8, 64), 256, 0, stream>>>(ob, wout_h, b_out, out);
}